// Round 1
// baseline (2823.680 us; speedup 1.0000x reference)
//
#include <hip/hip_runtime.h>
#include <math.h>

#define NN 25000
#define NE 100000
#define NE2 125000   // NE + NN self loops

static __device__ __forceinline__ void atomicMaxF(float* addr, float val) {
  if (val >= 0.f) {
    atomicMax((int*)addr, __float_as_int(val));
  } else {
    atomicMin((unsigned int*)addr, __float_as_uint(val));
  }
}

// ---------------- W transpose: Wt[(i*32+o)*32 + k] = W[k*1024 + i*32 + o] ----
__global__ void k_transpose_w(const float* __restrict__ W, float* __restrict__ Wt) {
  int t = blockIdx.x * blockDim.x + threadIdx.x;
  if (t >= 32 * 1024) return;
  int k = t >> 10;
  int io = t & 1023;
  Wt[io * 32 + k] = W[t];
}

// ---------------- node encoder + r1 init: h0 = x@We+be ; r1 = h0@root1+bias1 --
__global__ void k_encode_nodes(const float* __restrict__ x,
                               const float* __restrict__ We, const float* __restrict__ be,
                               const float* __restrict__ root1, const float* __restrict__ bias1,
                               float* __restrict__ h0, float* __restrict__ r1) {
  int n = blockIdx.x * blockDim.x + threadIdx.x;
  if (n >= NN) return;
  float xv[32], hv[32], rv[32];
#pragma unroll
  for (int i = 0; i < 8; i++) *(float4*)(xv + 4 * i) = *(const float4*)(x + n * 32 + 4 * i);
#pragma unroll
  for (int j = 0; j < 32; j++) hv[j] = be[j];
#pragma unroll
  for (int i = 0; i < 32; i++) {
    float xi = xv[i];
#pragma unroll
    for (int j = 0; j < 32; j++) hv[j] += xi * We[i * 32 + j];
  }
#pragma unroll
  for (int i = 0; i < 8; i++) *(float4*)(h0 + n * 32 + 4 * i) = *(float4*)(hv + 4 * i);
#pragma unroll
  for (int j = 0; j < 32; j++) rv[j] = bias1[j];
#pragma unroll
  for (int i = 0; i < 32; i++) {
    float hi = hv[i];
#pragma unroll
    for (int j = 0; j < 32; j++) rv[j] += hi * root1[i * 32 + j];
  }
#pragma unroll
  for (int i = 0; i < 8; i++) *(float4*)(r1 + n * 32 + 4 * i) = *(float4*)(rv + 4 * i);
}

// ---------------- edge encoder: ea = edge_attr@We_edge + be_edge -------------
__global__ void k_encode_edges(const float* __restrict__ eattr,
                               const float* __restrict__ We, const float* __restrict__ be,
                               float* __restrict__ ea) {
  int e = blockIdx.x * blockDim.x + threadIdx.x;
  if (e >= NE) return;
  float av[16], ov[32];
#pragma unroll
  for (int i = 0; i < 4; i++) *(float4*)(av + 4 * i) = *(const float4*)(eattr + e * 16 + 4 * i);
#pragma unroll
  for (int j = 0; j < 32; j++) ov[j] = be[j];
#pragma unroll
  for (int k = 0; k < 16; k++) {
    float ak = av[k];
#pragma unroll
    for (int j = 0; j < 32; j++) ov[j] += ak * We[k * 32 + j];
  }
#pragma unroll
  for (int i = 0; i < 8; i++) *(float4*)(ea + e * 32 + 4 * i) = *(float4*)(ov + 4 * i);
}

// ---------------- NNConv message + scatter-add -------------------------------
// thread t -> edge e = t>>1, output half ob = (t&1)*16
// msg[o] = sum_i h[src,i] * ( b[i*32+o] + sum_k ea[e,k]*Wt[(i*32+o)*32+k] )
__global__ void k_nnconv(const float* __restrict__ hin, const float* __restrict__ ea,
                         const float* __restrict__ Wt, const float* __restrict__ bnn,
                         const int* __restrict__ ei, float* __restrict__ acc) {
  int t = blockIdx.x * blockDim.x + threadIdx.x;
  if (t >= 2 * NE) return;
  int e = t >> 1;
  int ob = (t & 1) * 16;
  int s = ei[e];
  int d = ei[NE + e];
  float eav[32];
#pragma unroll
  for (int i = 0; i < 8; i++) *(float4*)(eav + 4 * i) = *(const float4*)(ea + e * 32 + 4 * i);
  float msg[16];
#pragma unroll
  for (int o = 0; o < 16; o++) msg[o] = 0.f;
  const float* hrow = hin + s * 32;
  for (int i = 0; i < 32; i++) {
    const float* wbase = Wt + i * 1024 + ob * 32;
    const float* bp = bnn + i * 32 + ob;
    float hi = hrow[i];
#pragma unroll
    for (int o = 0; o < 16; o++) {
      float a = bp[o];
      const float* wr = wbase + o * 32;
#pragma unroll
      for (int k4 = 0; k4 < 8; k4++) {
        float4 wv = *(const float4*)(wr + 4 * k4);
        a += eav[4 * k4 + 0] * wv.x;
        a += eav[4 * k4 + 1] * wv.y;
        a += eav[4 * k4 + 2] * wv.z;
        a += eav[4 * k4 + 3] * wv.w;
      }
      msg[o] += hi * a;
    }
  }
  float* ap = acc + d * 32 + ob;
#pragma unroll
  for (int o = 0; o < 16; o++) unsafeAtomicAdd(ap + o, msg[o]);
}

// ---------------- GAT prep: h1=relu(r1) in place; xl,xr; init m/denom/gacc ---
__global__ void k_gat_prep(float* __restrict__ r1,
                           const float* __restrict__ Wl, const float* __restrict__ bl,
                           const float* __restrict__ Wr, const float* __restrict__ br,
                           float* __restrict__ xl, float* __restrict__ xr,
                           float* __restrict__ m, float* __restrict__ denom,
                           float* __restrict__ gacc) {
  int n = blockIdx.x * blockDim.x + threadIdx.x;
  if (n >= NN) return;
  float hv[32];
#pragma unroll
  for (int i = 0; i < 8; i++) *(float4*)(hv + 4 * i) = *(const float4*)(r1 + n * 32 + 4 * i);
#pragma unroll
  for (int j = 0; j < 32; j++) hv[j] = fmaxf(hv[j], 0.f);
#pragma unroll
  for (int i = 0; i < 8; i++) *(float4*)(r1 + n * 32 + 4 * i) = *(float4*)(hv + 4 * i);
  float lv[32], rv[32];
#pragma unroll
  for (int j = 0; j < 32; j++) { lv[j] = bl[j]; rv[j] = br[j]; }
#pragma unroll
  for (int i = 0; i < 32; i++) {
    float hi = hv[i];
#pragma unroll
    for (int j = 0; j < 32; j++) {
      lv[j] += hi * Wl[i * 32 + j];
      rv[j] += hi * Wr[i * 32 + j];
    }
  }
#pragma unroll
  for (int i = 0; i < 8; i++) *(float4*)(xl + n * 32 + 4 * i) = *(float4*)(lv + 4 * i);
#pragma unroll
  for (int i = 0; i < 8; i++) *(float4*)(xr + n * 32 + 4 * i) = *(float4*)(rv + 4 * i);
#pragma unroll
  for (int hh = 0; hh < 4; hh++) { m[n * 4 + hh] = -INFINITY; denom[n * 4 + hh] = 0.f; }
  float4 z = make_float4(0.f, 0.f, 0.f, 0.f);
#pragma unroll
  for (int i = 0; i < 8; i++) *(float4*)(gacc + n * 32 + 4 * i) = z;
}

// ---------------- GAT pass A: logits + segment max ---------------------------
__global__ void k_gat_logits(const int* __restrict__ ei,
                             const float* __restrict__ xl, const float* __restrict__ xr,
                             const float* __restrict__ att,
                             float* __restrict__ la, float* __restrict__ m) {
  int e2 = blockIdx.x * blockDim.x + threadIdx.x;
  if (e2 >= NE2) return;
  int s, d;
  if (e2 < NE) { s = ei[e2]; d = ei[NE + e2]; } else { s = e2 - NE; d = s; }
  float lv[32], rv[32];
#pragma unroll
  for (int i = 0; i < 8; i++) *(float4*)(lv + 4 * i) = *(const float4*)(xl + s * 32 + 4 * i);
#pragma unroll
  for (int i = 0; i < 8; i++) *(float4*)(rv + 4 * i) = *(const float4*)(xr + d * 32 + 4 * i);
#pragma unroll
  for (int hh = 0; hh < 4; hh++) {
    float acc = 0.f;
#pragma unroll
    for (int dg = 0; dg < 8; dg++) {
      float v = lv[hh * 8 + dg] + rv[hh * 8 + dg];
      v = (v > 0.f) ? v : 0.2f * v;
      acc += v * att[hh * 8 + dg];
    }
    la[e2 * 4 + hh] = acc;
    atomicMaxF(&m[d * 4 + hh], acc);
  }
}

// ---------------- GAT pass B: a = exp(logit - m[d]); denom += a --------------
__global__ void k_gat_a(const int* __restrict__ ei,
                        float* __restrict__ la, const float* __restrict__ m,
                        float* __restrict__ denom) {
  int t = blockIdx.x * blockDim.x + threadIdx.x;
  if (t >= NE2 * 4) return;
  int e2 = t >> 2, hh = t & 3;
  int d = (e2 < NE) ? ei[NE + e2] : (e2 - NE);
  float a = expf(la[t] - m[d * 4 + hh]);
  la[t] = a;
  unsafeAtomicAdd(&denom[d * 4 + hh], a);
}

// ---------------- GAT pass C: gacc[d] += alpha * xl[s] -----------------------
__global__ void k_gat_scatter(const int* __restrict__ ei,
                              const float* __restrict__ xl, const float* __restrict__ la,
                              const float* __restrict__ denom, float* __restrict__ gacc) {
  int e2 = blockIdx.x * blockDim.x + threadIdx.x;
  if (e2 >= NE2) return;
  int s, d;
  if (e2 < NE) { s = ei[e2]; d = ei[NE + e2]; } else { s = e2 - NE; d = s; }
  float alpha[4];
#pragma unroll
  for (int hh = 0; hh < 4; hh++)
    alpha[hh] = la[e2 * 4 + hh] / (denom[d * 4 + hh] + 1e-16f);
  float lv[32];
#pragma unroll
  for (int i = 0; i < 8; i++) *(float4*)(lv + 4 * i) = *(const float4*)(xl + s * 32 + 4 * i);
#pragma unroll
  for (int hh = 0; hh < 4; hh++) {
#pragma unroll
    for (int dg = 0; dg < 8; dg++) {
      unsafeAtomicAdd(&gacc[d * 32 + hh * 8 + dg], alpha[hh] * lv[hh * 8 + dg]);
    }
  }
}

// ---------------- GAT finish: h2 = relu(gacc+bias_gat); r2 = h2@root2+bias2 --
__global__ void k_gat_finish(const float* __restrict__ gacc, const float* __restrict__ bias_gat,
                             const float* __restrict__ root2, const float* __restrict__ bias2,
                             float* __restrict__ h2, float* __restrict__ r2) {
  int n = blockIdx.x * blockDim.x + threadIdx.x;
  if (n >= NN) return;
  float hv[32], rv[32];
#pragma unroll
  for (int i = 0; i < 8; i++) *(float4*)(hv + 4 * i) = *(const float4*)(gacc + n * 32 + 4 * i);
#pragma unroll
  for (int j = 0; j < 32; j++) hv[j] = fmaxf(hv[j] + bias_gat[j], 0.f);
#pragma unroll
  for (int i = 0; i < 8; i++) *(float4*)(h2 + n * 32 + 4 * i) = *(float4*)(hv + 4 * i);
#pragma unroll
  for (int j = 0; j < 32; j++) rv[j] = bias2[j];
#pragma unroll
  for (int i = 0; i < 32; i++) {
    float hi = hv[i];
#pragma unroll
    for (int j = 0; j < 32; j++) rv[j] += hi * root2[i * 32 + j];
  }
#pragma unroll
  for (int i = 0; i < 8; i++) *(float4*)(r2 + n * 32 + 4 * i) = *(float4*)(rv + 4 * i);
}

// ---------------- classifier: out = relu(r2) @ Wlin + blin -------------------
__global__ void k_final(const float* __restrict__ r2, const float* __restrict__ Wlin,
                        const float* __restrict__ blin, float* __restrict__ out) {
  int n = blockIdx.x * blockDim.x + threadIdx.x;
  if (n >= NN) return;
  float hv[32];
#pragma unroll
  for (int i = 0; i < 8; i++) *(float4*)(hv + 4 * i) = *(const float4*)(r2 + n * 32 + 4 * i);
#pragma unroll
  for (int j = 0; j < 32; j++) hv[j] = fmaxf(hv[j], 0.f);
  float ov[10];
#pragma unroll
  for (int c = 0; c < 10; c++) ov[c] = blin[c];
#pragma unroll
  for (int j = 0; j < 32; j++) {
    float hj = hv[j];
#pragma unroll
    for (int c = 0; c < 10; c++) ov[c] += hj * Wlin[j * 10 + c];
  }
#pragma unroll
  for (int c = 0; c < 10; c++) out[n * 10 + c] = ov[c];
}

extern "C" void kernel_launch(void* const* d_in, const int* in_sizes, int n_in,
                              void* d_out, int out_size, void* d_ws, size_t ws_size,
                              hipStream_t stream) {
  const float* x         = (const float*)d_in[0];
  const float* edge_attr = (const float*)d_in[1];
  const int*   ei        = (const int*)d_in[2];   // [2,E]: src = ei, dst = ei+NE
  const float* We_node   = (const float*)d_in[3];
  const float* be_node   = (const float*)d_in[4];
  const float* We_edge   = (const float*)d_in[5];
  const float* be_edge   = (const float*)d_in[6];
  const float* W1_nn     = (const float*)d_in[7];
  const float* b1_nn     = (const float*)d_in[8];
  const float* root1     = (const float*)d_in[9];
  const float* bias1     = (const float*)d_in[10];
  const float* Wl        = (const float*)d_in[11];
  const float* bl        = (const float*)d_in[12];
  const float* Wr        = (const float*)d_in[13];
  const float* br        = (const float*)d_in[14];
  const float* att       = (const float*)d_in[15];
  const float* bias_gat  = (const float*)d_in[16];
  const float* W2_nn     = (const float*)d_in[17];
  const float* b2_nn     = (const float*)d_in[18];
  const float* root2     = (const float*)d_in[19];
  const float* bias2     = (const float*)d_in[20];
  const float* Wlin      = (const float*)d_in[21];
  const float* blin      = (const float*)d_in[22];
  float* out = (float*)d_out;

  float* ws = (float*)d_ws;
  float* h0    = ws;                 // NN*32
  float* ea    = h0 + NN * 32;       // NE*32
  float* r1    = ea + NE * 32;       // NN*32  (conv1 acc -> h1 in place)
  float* xl    = r1 + NN * 32;       // NN*32
  float* xr    = xl + NN * 32;       // NN*32
  float* m     = xr + NN * 32;       // NN*4
  float* denom = m + NN * 4;         // NN*4
  float* la    = denom + NN * 4;     // NE2*4
  float* gacc  = la + NE2 * 4;       // NN*32
  float* r2    = gacc + NN * 32;     // NN*32
  float* Wt1   = r2 + NN * 32;       // 32*1024
  float* Wt2   = Wt1 + 32 * 1024;    // 32*1024

  const int B = 256;
  k_transpose_w<<<(32 * 1024 + B - 1) / B, B, 0, stream>>>(W1_nn, Wt1);
  k_transpose_w<<<(32 * 1024 + B - 1) / B, B, 0, stream>>>(W2_nn, Wt2);
  k_encode_nodes<<<(NN + B - 1) / B, B, 0, stream>>>(x, We_node, be_node, root1, bias1, h0, r1);
  k_encode_edges<<<(NE + B - 1) / B, B, 0, stream>>>(edge_attr, We_edge, be_edge, ea);
  k_nnconv<<<(2 * NE + B - 1) / B, B, 0, stream>>>(h0, ea, Wt1, b1_nn, ei, r1);
  k_gat_prep<<<(NN + B - 1) / B, B, 0, stream>>>(r1, Wl, bl, Wr, br, xl, xr, m, denom, gacc);
  k_gat_logits<<<(NE2 + B - 1) / B, B, 0, stream>>>(ei, xl, xr, att, la, m);
  k_gat_a<<<(NE2 * 4 + B - 1) / B, B, 0, stream>>>(ei, la, m, denom);
  k_gat_scatter<<<(NE2 + B - 1) / B, B, 0, stream>>>(ei, xl, la, denom, gacc);
  k_gat_finish<<<(NN + B - 1) / B, B, 0, stream>>>(gacc, bias_gat, root2, bias2, h0, r2);
  k_nnconv<<<(2 * NE + B - 1) / B, B, 0, stream>>>(h0, ea, Wt2, b2_nn, ei, r2);
  k_final<<<(NN + B - 1) / B, B, 0, stream>>>(r2, Wlin, blin, out);
}

// Round 2
// 387.077 us; speedup vs baseline: 7.2949x; 7.2949x over previous
//
#include <hip/hip_runtime.h>
#include <hip/hip_bf16.h>
#include <math.h>

#define NN 25000
#define NE 100000
#define NE2 125000   // NE + NN self loops
#define NTILES (NE / 16)   // 6250 edge tiles of 16

typedef __attribute__((ext_vector_type(8))) short short8;
typedef __attribute__((ext_vector_type(4))) float f32x4;

static __device__ __forceinline__ void atomicMaxF(float* addr, float val) {
  if (val >= 0.f) {
    atomicMax((int*)addr, __float_as_int(val));
  } else {
    atomicMin((unsigned int*)addr, __float_as_uint(val));
  }
}

static __device__ __forceinline__ short f2bf(float f) {
  union { __hip_bfloat16 h; short s; } cv;
  cv.h = __float2bfloat16(f);
  return cv.s;
}

// ---- pack W_nn (+ bias row) into MFMA B-fragment order, bf16 ----------------
// Bswz[((t*2+nt)*64 + l)*8 + j] = (t<32 ? W[t*1024 + i*32 + o] : b[i*32 + o])
//   with i = 8*(l>>4)+j, o = nt*16 + (l&15).  33*2*64*8 = 33792 elems.
__global__ void k_pack_w(const float* __restrict__ W, const float* __restrict__ b,
                         __hip_bfloat16* __restrict__ Bswz) {
  int idx = blockIdx.x * blockDim.x + threadIdx.x;
  if (idx >= 33 * 2 * 64 * 8) return;
  int j = idx & 7;
  int l = (idx >> 3) & 63;
  int nt = (idx >> 9) & 1;
  int t = idx >> 10;
  int i = 8 * (l >> 4) + j;
  int o = nt * 16 + (l & 15);
  float v = (t < 32) ? W[t * 1024 + i * 32 + o] : b[i * 32 + o];
  Bswz[idx] = __float2bfloat16(v);
}

// ---- NNConv as MFMA GEMM: msg = Z @ Wf, Z[e, t*32+i] = ea[e,t]*h[src,i] -----
// wave handles a 16-edge tile; 32 LDS K-steps + 1 global bias step; atomic scatter.
__global__ void __launch_bounds__(256) k_nnconv_mfma(
    const float* __restrict__ hin, const float* __restrict__ ea,
    const __hip_bfloat16* __restrict__ Bswz, const int* __restrict__ ei,
    float* __restrict__ acc) {
  extern __shared__ short8 bsh[];   // 32 steps * 2 ntiles * 64 lanes = 64 KB
  int tid = threadIdx.x;
  // stage first 32 K-steps of Bswz into LDS (65536 B = 4096 uint4)
  {
    uint4* s4 = (uint4*)bsh;
    const uint4* g4 = (const uint4*)Bswz;
#pragma unroll
    for (int it = 0; it < 16; it++) s4[tid + 256 * it] = g4[tid + 256 * it];
  }
  __syncthreads();

  int wid = tid >> 6;
  int lane = tid & 63;
  int lrow = lane & 15;        // A row / C col
  int lk8 = (lane >> 4) * 8;   // k-offset of this lane's 8 A elems
  const int* dstp = ei + NE;

  for (int tile = blockIdx.x * 4 + wid; tile < NTILES; tile += gridDim.x * 4) {
    int e0 = tile * 16;
    int e = e0 + lrow;
    int src = ei[e];
    // h fragment: h[src, lk8 .. lk8+8)
    float hf[8];
    *(float4*)(hf)     = *(const float4*)(hin + src * 32 + lk8);
    *(float4*)(hf + 4) = *(const float4*)(hin + src * 32 + lk8 + 4);
    // ea row of this edge (4-way lane redundancy, L1-served)
    float eav[32];
#pragma unroll
    for (int c = 0; c < 8; c++)
      *(float4*)(eav + 4 * c) = *(const float4*)(ea + e * 32 + 4 * c);

    f32x4 a00 = {0.f, 0.f, 0.f, 0.f}, a01 = a00, a10 = a00, a11 = a00;
#pragma unroll
    for (int t = 0; t < 32; t++) {
      float et = eav[t];
      short8 af;
#pragma unroll
      for (int j = 0; j < 8; j++) af[j] = f2bf(et * hf[j]);
      short8 b0 = bsh[(t * 2 + 0) * 64 + lane];
      short8 b1 = bsh[(t * 2 + 1) * 64 + lane];
      if (t & 1) {
        a01 = __builtin_amdgcn_mfma_f32_16x16x32_bf16(af, b0, a01, 0, 0, 0);
        a11 = __builtin_amdgcn_mfma_f32_16x16x32_bf16(af, b1, a11, 0, 0, 0);
      } else {
        a00 = __builtin_amdgcn_mfma_f32_16x16x32_bf16(af, b0, a00, 0, 0, 0);
        a10 = __builtin_amdgcn_mfma_f32_16x16x32_bf16(af, b1, a10, 0, 0, 0);
      }
    }
    // bias K-step (t=32): A = h itself, B from global (L2-cached)
    {
      short8 af;
#pragma unroll
      for (int j = 0; j < 8; j++) af[j] = f2bf(hf[j]);
      const short8* gb = (const short8*)Bswz;
      short8 b0 = gb[(32 * 2 + 0) * 64 + lane];
      short8 b1 = gb[(32 * 2 + 1) * 64 + lane];
      a00 = __builtin_amdgcn_mfma_f32_16x16x32_bf16(af, b0, a00, 0, 0, 0);
      a10 = __builtin_amdgcn_mfma_f32_16x16x32_bf16(af, b1, a10, 0, 0, 0);
    }
    f32x4 c0 = a00 + a01;
    f32x4 c1 = a10 + a11;
    // scatter: lane holds C[row=(lane>>4)*4+r][col=lrow (+16)]
    int r0 = e0 + (lane >> 4) * 4;
#pragma unroll
    for (int r = 0; r < 4; r++) {
      int d = dstp[r0 + r];
      float* ap = acc + d * 32 + lrow;
      unsafeAtomicAdd(ap, c0[r]);
      unsafeAtomicAdd(ap + 16, c1[r]);
    }
  }
}

// ---------------- node encoder + r1 init: h0 = x@We+be ; r1 = h0@root1+bias1 --
__global__ void k_encode_nodes(const float* __restrict__ x,
                               const float* __restrict__ We, const float* __restrict__ be,
                               const float* __restrict__ root1, const float* __restrict__ bias1,
                               float* __restrict__ h0, float* __restrict__ r1) {
  int n = blockIdx.x * blockDim.x + threadIdx.x;
  if (n >= NN) return;
  float xv[32], hv[32], rv[32];
#pragma unroll
  for (int i = 0; i < 8; i++) *(float4*)(xv + 4 * i) = *(const float4*)(x + n * 32 + 4 * i);
#pragma unroll
  for (int j = 0; j < 32; j++) hv[j] = be[j];
#pragma unroll
  for (int i = 0; i < 32; i++) {
    float xi = xv[i];
#pragma unroll
    for (int j = 0; j < 32; j++) hv[j] += xi * We[i * 32 + j];
  }
#pragma unroll
  for (int i = 0; i < 8; i++) *(float4*)(h0 + n * 32 + 4 * i) = *(float4*)(hv + 4 * i);
#pragma unroll
  for (int j = 0; j < 32; j++) rv[j] = bias1[j];
#pragma unroll
  for (int i = 0; i < 32; i++) {
    float hi = hv[i];
#pragma unroll
    for (int j = 0; j < 32; j++) rv[j] += hi * root1[i * 32 + j];
  }
#pragma unroll
  for (int i = 0; i < 8; i++) *(float4*)(r1 + n * 32 + 4 * i) = *(float4*)(rv + 4 * i);
}

// ---------------- edge encoder: ea = edge_attr@We_edge + be_edge -------------
__global__ void k_encode_edges(const float* __restrict__ eattr,
                               const float* __restrict__ We, const float* __restrict__ be,
                               float* __restrict__ ea) {
  int e = blockIdx.x * blockDim.x + threadIdx.x;
  if (e >= NE) return;
  float av[16], ov[32];
#pragma unroll
  for (int i = 0; i < 4; i++) *(float4*)(av + 4 * i) = *(const float4*)(eattr + e * 16 + 4 * i);
#pragma unroll
  for (int j = 0; j < 32; j++) ov[j] = be[j];
#pragma unroll
  for (int k = 0; k < 16; k++) {
    float ak = av[k];
#pragma unroll
    for (int j = 0; j < 32; j++) ov[j] += ak * We[k * 32 + j];
  }
#pragma unroll
  for (int i = 0; i < 8; i++) *(float4*)(ea + e * 32 + 4 * i) = *(float4*)(ov + 4 * i);
}

// ---------------- GAT prep: h1=relu(r1) in place; xl,xr; init m/denom/gacc ---
__global__ void k_gat_prep(float* __restrict__ r1,
                           const float* __restrict__ Wl, const float* __restrict__ bl,
                           const float* __restrict__ Wr, const float* __restrict__ br,
                           float* __restrict__ xl, float* __restrict__ xr,
                           float* __restrict__ m, float* __restrict__ denom,
                           float* __restrict__ gacc) {
  int n = blockIdx.x * blockDim.x + threadIdx.x;
  if (n >= NN) return;
  float hv[32];
#pragma unroll
  for (int i = 0; i < 8; i++) *(float4*)(hv + 4 * i) = *(const float4*)(r1 + n * 32 + 4 * i);
#pragma unroll
  for (int j = 0; j < 32; j++) hv[j] = fmaxf(hv[j], 0.f);
#pragma unroll
  for (int i = 0; i < 8; i++) *(float4*)(r1 + n * 32 + 4 * i) = *(float4*)(hv + 4 * i);
  float lv[32], rv[32];
#pragma unroll
  for (int j = 0; j < 32; j++) { lv[j] = bl[j]; rv[j] = br[j]; }
#pragma unroll
  for (int i = 0; i < 32; i++) {
    float hi = hv[i];
#pragma unroll
    for (int j = 0; j < 32; j++) {
      lv[j] += hi * Wl[i * 32 + j];
      rv[j] += hi * Wr[i * 32 + j];
    }
  }
#pragma unroll
  for (int i = 0; i < 8; i++) *(float4*)(xl + n * 32 + 4 * i) = *(float4*)(lv + 4 * i);
#pragma unroll
  for (int i = 0; i < 8; i++) *(float4*)(xr + n * 32 + 4 * i) = *(float4*)(rv + 4 * i);
#pragma unroll
  for (int hh = 0; hh < 4; hh++) { m[n * 4 + hh] = -INFINITY; denom[n * 4 + hh] = 0.f; }
  float4 z = make_float4(0.f, 0.f, 0.f, 0.f);
#pragma unroll
  for (int i = 0; i < 8; i++) *(float4*)(gacc + n * 32 + 4 * i) = z;
}

// ---------------- GAT pass A: logits + segment max ---------------------------
__global__ void k_gat_logits(const int* __restrict__ ei,
                             const float* __restrict__ xl, const float* __restrict__ xr,
                             const float* __restrict__ att,
                             float* __restrict__ la, float* __restrict__ m) {
  int e2 = blockIdx.x * blockDim.x + threadIdx.x;
  if (e2 >= NE2) return;
  int s, d;
  if (e2 < NE) { s = ei[e2]; d = ei[NE + e2]; } else { s = e2 - NE; d = s; }
  float lv[32], rv[32];
#pragma unroll
  for (int i = 0; i < 8; i++) *(float4*)(lv + 4 * i) = *(const float4*)(xl + s * 32 + 4 * i);
#pragma unroll
  for (int i = 0; i < 8; i++) *(float4*)(rv + 4 * i) = *(const float4*)(xr + d * 32 + 4 * i);
#pragma unroll
  for (int hh = 0; hh < 4; hh++) {
    float acc = 0.f;
#pragma unroll
    for (int dg = 0; dg < 8; dg++) {
      float v = lv[hh * 8 + dg] + rv[hh * 8 + dg];
      v = (v > 0.f) ? v : 0.2f * v;
      acc += v * att[hh * 8 + dg];
    }
    la[e2 * 4 + hh] = acc;
    atomicMaxF(&m[d * 4 + hh], acc);
  }
}

// ---------------- GAT pass B: a = exp(logit - m[d]); denom += a --------------
__global__ void k_gat_a(const int* __restrict__ ei,
                        float* __restrict__ la, const float* __restrict__ m,
                        float* __restrict__ denom) {
  int t = blockIdx.x * blockDim.x + threadIdx.x;
  if (t >= NE2 * 4) return;
  int e2 = t >> 2, hh = t & 3;
  int d = (e2 < NE) ? ei[NE + e2] : (e2 - NE);
  float a = expf(la[t] - m[d * 4 + hh]);
  la[t] = a;
  unsafeAtomicAdd(&denom[d * 4 + hh], a);
}

// ---------------- GAT pass C: gacc[d] += alpha * xl[s] -----------------------
__global__ void k_gat_scatter(const int* __restrict__ ei,
                              const float* __restrict__ xl, const float* __restrict__ la,
                              const float* __restrict__ denom, float* __restrict__ gacc) {
  int e2 = blockIdx.x * blockDim.x + threadIdx.x;
  if (e2 >= NE2) return;
  int s, d;
  if (e2 < NE) { s = ei[e2]; d = ei[NE + e2]; } else { s = e2 - NE; d = s; }
  float alpha[4];
#pragma unroll
  for (int hh = 0; hh < 4; hh++)
    alpha[hh] = la[e2 * 4 + hh] / (denom[d * 4 + hh] + 1e-16f);
  float lv[32];
#pragma unroll
  for (int i = 0; i < 8; i++) *(float4*)(lv + 4 * i) = *(const float4*)(xl + s * 32 + 4 * i);
#pragma unroll
  for (int hh = 0; hh < 4; hh++) {
#pragma unroll
    for (int dg = 0; dg < 8; dg++) {
      unsafeAtomicAdd(&gacc[d * 32 + hh * 8 + dg], alpha[hh] * lv[hh * 8 + dg]);
    }
  }
}

// ---------------- GAT finish: h2 = relu(gacc+bias_gat); r2 = h2@root2+bias2 --
__global__ void k_gat_finish(const float* __restrict__ gacc, const float* __restrict__ bias_gat,
                             const float* __restrict__ root2, const float* __restrict__ bias2,
                             float* __restrict__ h2, float* __restrict__ r2) {
  int n = blockIdx.x * blockDim.x + threadIdx.x;
  if (n >= NN) return;
  float hv[32], rv[32];
#pragma unroll
  for (int i = 0; i < 8; i++) *(float4*)(hv + 4 * i) = *(const float4*)(gacc + n * 32 + 4 * i);
#pragma unroll
  for (int j = 0; j < 32; j++) hv[j] = fmaxf(hv[j] + bias_gat[j], 0.f);
#pragma unroll
  for (int i = 0; i < 8; i++) *(float4*)(h2 + n * 32 + 4 * i) = *(float4*)(hv + 4 * i);
#pragma unroll
  for (int j = 0; j < 32; j++) rv[j] = bias2[j];
#pragma unroll
  for (int i = 0; i < 32; i++) {
    float hi = hv[i];
#pragma unroll
    for (int j = 0; j < 32; j++) rv[j] += hi * root2[i * 32 + j];
  }
#pragma unroll
  for (int i = 0; i < 8; i++) *(float4*)(r2 + n * 32 + 4 * i) = *(float4*)(rv + 4 * i);
}

// ---------------- classifier: out = relu(r2) @ Wlin + blin -------------------
__global__ void k_final(const float* __restrict__ r2, const float* __restrict__ Wlin,
                        const float* __restrict__ blin, float* __restrict__ out) {
  int n = blockIdx.x * blockDim.x + threadIdx.x;
  if (n >= NN) return;
  float hv[32];
#pragma unroll
  for (int i = 0; i < 8; i++) *(float4*)(hv + 4 * i) = *(const float4*)(r2 + n * 32 + 4 * i);
#pragma unroll
  for (int j = 0; j < 32; j++) hv[j] = fmaxf(hv[j], 0.f);
  float ov[10];
#pragma unroll
  for (int c = 0; c < 10; c++) ov[c] = blin[c];
#pragma unroll
  for (int j = 0; j < 32; j++) {
    float hj = hv[j];
#pragma unroll
    for (int c = 0; c < 10; c++) ov[c] += hj * Wlin[j * 10 + c];
  }
#pragma unroll
  for (int c = 0; c < 10; c++) out[n * 10 + c] = ov[c];
}

extern "C" void kernel_launch(void* const* d_in, const int* in_sizes, int n_in,
                              void* d_out, int out_size, void* d_ws, size_t ws_size,
                              hipStream_t stream) {
  const float* x         = (const float*)d_in[0];
  const float* edge_attr = (const float*)d_in[1];
  const int*   ei        = (const int*)d_in[2];   // [2,E]: src = ei, dst = ei+NE
  const float* We_node   = (const float*)d_in[3];
  const float* be_node   = (const float*)d_in[4];
  const float* We_edge   = (const float*)d_in[5];
  const float* be_edge   = (const float*)d_in[6];
  const float* W1_nn     = (const float*)d_in[7];
  const float* b1_nn     = (const float*)d_in[8];
  const float* root1     = (const float*)d_in[9];
  const float* bias1     = (const float*)d_in[10];
  const float* Wl        = (const float*)d_in[11];
  const float* bl        = (const float*)d_in[12];
  const float* Wr        = (const float*)d_in[13];
  const float* br        = (const float*)d_in[14];
  const float* att       = (const float*)d_in[15];
  const float* bias_gat  = (const float*)d_in[16];
  const float* W2_nn     = (const float*)d_in[17];
  const float* b2_nn     = (const float*)d_in[18];
  const float* root2     = (const float*)d_in[19];
  const float* bias2     = (const float*)d_in[20];
  const float* Wlin      = (const float*)d_in[21];
  const float* blin      = (const float*)d_in[22];
  float* out = (float*)d_out;

  float* ws = (float*)d_ws;
  float* h0    = ws;                 // NN*32  (h0, later h2)
  float* ea    = h0 + NN * 32;       // NE*32
  float* r1    = ea + NE * 32;       // NN*32  (conv1 acc -> h1 in place)
  float* xl    = r1 + NN * 32;       // NN*32
  float* xr    = xl + NN * 32;       // NN*32
  float* m     = xr + NN * 32;       // NN*4
  float* denom = m + NN * 4;         // NN*4
  float* la    = denom + NN * 4;     // NE2*4
  float* gacc  = la + NE2 * 4;       // NN*32
  float* r2    = gacc + NN * 32;     // NN*32
  __hip_bfloat16* Bswz1 = (__hip_bfloat16*)(r2 + NN * 32);      // 33792 bf16
  __hip_bfloat16* Bswz2 = (__hip_bfloat16*)(r2 + NN * 32 + 17000); // 33792 bf16

  const int B = 256;
  k_pack_w<<<132, B, 0, stream>>>(W1_nn, b1_nn, Bswz1);
  k_pack_w<<<132, B, 0, stream>>>(W2_nn, b2_nn, Bswz2);
  k_encode_nodes<<<(NN + B - 1) / B, B, 0, stream>>>(x, We_node, be_node, root1, bias1, h0, r1);
  k_encode_edges<<<(NE + B - 1) / B, B, 0, stream>>>(edge_attr, We_edge, be_edge, ea);
  k_nnconv_mfma<<<512, B, 65536, stream>>>(h0, ea, Bswz1, ei, r1);
  k_gat_prep<<<(NN + B - 1) / B, B, 0, stream>>>(r1, Wl, bl, Wr, br, xl, xr, m, denom, gacc);
  k_gat_logits<<<(NE2 + B - 1) / B, B, 0, stream>>>(ei, xl, xr, att, la, m);
  k_gat_a<<<(NE2 * 4 + B - 1) / B, B, 0, stream>>>(ei, la, m, denom);
  k_gat_scatter<<<(NE2 + B - 1) / B, B, 0, stream>>>(ei, xl, la, denom, gacc);
  k_gat_finish<<<(NN + B - 1) / B, B, 0, stream>>>(gacc, bias_gat, root2, bias2, h0, r2);
  k_nnconv_mfma<<<512, B, 65536, stream>>>(h0, ea, Bswz2, ei, r2);
  k_final<<<(NN + B - 1) / B, B, 0, stream>>>(r2, Wlin, blin, out);
}

// Round 3
// 234.640 us; speedup vs baseline: 12.0341x; 1.6497x over previous
//
#include <hip/hip_runtime.h>
#include <hip/hip_bf16.h>
#include <math.h>

#define NN 25000
#define NE 100000
#define NE2 125000         // NE + NN self loops
#define NTILES (NE / 16)   // 6250 edge tiles of 16

typedef __attribute__((ext_vector_type(8))) short short8;
typedef __attribute__((ext_vector_type(4))) float f32x4;

static __device__ __forceinline__ short f2bf(float f) {
  union { __hip_bfloat16 h; short s; } cv;
  cv.h = __float2bfloat16(f);
  return cv.s;
}

// ============================ CSR build (by dst) =============================
__global__ void k_csr_init(int* __restrict__ deg) {
  int n = blockIdx.x * blockDim.x + threadIdx.x;
  if (n < NN) deg[n] = 1;   // self loop
}

__global__ void k_csr_count(const int* __restrict__ ei, int* __restrict__ deg) {
  int e = blockIdx.x * blockDim.x + threadIdx.x;
  if (e < NE) atomicAdd(&deg[ei[NE + e]], 1);
}

__global__ void __launch_bounds__(1024) k_csr_scan(const int* __restrict__ deg,
                                                   int* __restrict__ off,
                                                   int* __restrict__ cursor) {
  __shared__ int part[1024];
  int tid = threadIdx.x;
  const int CH = 25;  // 1024*25 = 25600 >= NN
  int base = tid * CH;
  int s = 0;
  for (int i = 0; i < CH; i++) {
    int n = base + i;
    if (n < NN) s += deg[n];
  }
  part[tid] = s;
  __syncthreads();
  for (int d = 1; d < 1024; d <<= 1) {
    int v = (tid >= d) ? part[tid - d] : 0;
    __syncthreads();
    part[tid] += v;
    __syncthreads();
  }
  int run = (tid > 0) ? part[tid - 1] : 0;
  for (int i = 0; i < CH; i++) {
    int n = base + i;
    if (n < NN) {
      off[n] = run;
      cursor[n] = run;
      run += deg[n];
    }
  }
}

__global__ void k_csr_fill(const int* __restrict__ ei, int* __restrict__ cursor,
                           int* __restrict__ slot) {
  int e2 = blockIdx.x * blockDim.x + threadIdx.x;
  if (e2 >= NE2) return;
  int d = (e2 < NE) ? ei[NE + e2] : (e2 - NE);
  int p = atomicAdd(&cursor[d], 1);
  slot[p] = e2;
}

// ---- pack W_nn (+ bias row) into MFMA B-fragment order, bf16 ----------------
__global__ void k_pack_w(const float* __restrict__ W, const float* __restrict__ b,
                         __hip_bfloat16* __restrict__ Bswz) {
  int idx = blockIdx.x * blockDim.x + threadIdx.x;
  if (idx >= 33 * 2 * 64 * 8) return;
  int j = idx & 7;
  int l = (idx >> 3) & 63;
  int nt = (idx >> 9) & 1;
  int t = idx >> 10;
  int i = 8 * (l >> 4) + j;
  int o = nt * 16 + (l & 15);
  float v = (t < 32) ? W[t * 1024 + i * 32 + o] : b[i * 32 + o];
  Bswz[idx] = __float2bfloat16(v);
}

// ---- NNConv as MFMA GEMM; epilogue = coalesced stores to msgbuf -------------
__global__ void __launch_bounds__(256) k_nnconv_mfma(
    const float* __restrict__ hin, const float* __restrict__ ea,
    const __hip_bfloat16* __restrict__ Bswz, const int* __restrict__ ei,
    float* __restrict__ msgbuf) {
  extern __shared__ short8 bsh[];   // 32 steps * 2 ntiles * 64 lanes = 64 KB
  int tid = threadIdx.x;
  {
    uint4* s4 = (uint4*)bsh;
    const uint4* g4 = (const uint4*)Bswz;
#pragma unroll
    for (int it = 0; it < 16; it++) s4[tid + 256 * it] = g4[tid + 256 * it];
  }
  __syncthreads();

  int wid = tid >> 6;
  int lane = tid & 63;
  int lrow = lane & 15;        // A row / C col
  int lk8 = (lane >> 4) * 8;   // k-offset of this lane's 8 A elems

  for (int tile = blockIdx.x * 4 + wid; tile < NTILES; tile += gridDim.x * 4) {
    int e0 = tile * 16;
    int e = e0 + lrow;
    int src = ei[e];
    float hf[8];
    *(float4*)(hf)     = *(const float4*)(hin + src * 32 + lk8);
    *(float4*)(hf + 4) = *(const float4*)(hin + src * 32 + lk8 + 4);
    float eav[32];
#pragma unroll
    for (int c = 0; c < 8; c++)
      *(float4*)(eav + 4 * c) = *(const float4*)(ea + e * 32 + 4 * c);

    f32x4 a00 = {0.f, 0.f, 0.f, 0.f}, a01 = a00, a10 = a00, a11 = a00;
#pragma unroll
    for (int t = 0; t < 32; t++) {
      float et = eav[t];
      short8 af;
#pragma unroll
      for (int j = 0; j < 8; j++) af[j] = f2bf(et * hf[j]);
      short8 b0 = bsh[(t * 2 + 0) * 64 + lane];
      short8 b1 = bsh[(t * 2 + 1) * 64 + lane];
      if (t & 1) {
        a01 = __builtin_amdgcn_mfma_f32_16x16x32_bf16(af, b0, a01, 0, 0, 0);
        a11 = __builtin_amdgcn_mfma_f32_16x16x32_bf16(af, b1, a11, 0, 0, 0);
      } else {
        a00 = __builtin_amdgcn_mfma_f32_16x16x32_bf16(af, b0, a00, 0, 0, 0);
        a10 = __builtin_amdgcn_mfma_f32_16x16x32_bf16(af, b1, a10, 0, 0, 0);
      }
    }
    // bias K-step (t=32): A = h itself, B from global (L2-cached)
    {
      short8 af;
#pragma unroll
      for (int j = 0; j < 8; j++) af[j] = f2bf(hf[j]);
      const short8* gb = (const short8*)Bswz;
      short8 b0 = gb[(32 * 2 + 0) * 64 + lane];
      short8 b1 = gb[(32 * 2 + 1) * 64 + lane];
      a00 = __builtin_amdgcn_mfma_f32_16x16x32_bf16(af, b0, a00, 0, 0, 0);
      a10 = __builtin_amdgcn_mfma_f32_16x16x32_bf16(af, b1, a10, 0, 0, 0);
    }
    f32x4 c0 = a00 + a01;
    f32x4 c1 = a10 + a11;
    int r0 = (lane >> 4) * 4;
#pragma unroll
    for (int r = 0; r < 4; r++) {
      float* mp = msgbuf + (e0 + r0 + r) * 32 + lrow;
      mp[0]  = c0[r];
      mp[16] = c1[r];
    }
  }
}

// ---------------- node encoder: h0 = x@We+be ; r1pre = h0@root1+bias1 --------
__global__ void k_encode_nodes(const float* __restrict__ x,
                               const float* __restrict__ We, const float* __restrict__ be,
                               const float* __restrict__ root1, const float* __restrict__ bias1,
                               float* __restrict__ h0, float* __restrict__ r1pre) {
  int n = blockIdx.x * blockDim.x + threadIdx.x;
  if (n >= NN) return;
  float xv[32], hv[32], rv[32];
#pragma unroll
  for (int i = 0; i < 8; i++) *(float4*)(xv + 4 * i) = *(const float4*)(x + n * 32 + 4 * i);
#pragma unroll
  for (int j = 0; j < 32; j++) hv[j] = be[j];
#pragma unroll
  for (int i = 0; i < 32; i++) {
    float xi = xv[i];
#pragma unroll
    for (int j = 0; j < 32; j++) hv[j] += xi * We[i * 32 + j];
  }
#pragma unroll
  for (int i = 0; i < 8; i++) *(float4*)(h0 + n * 32 + 4 * i) = *(float4*)(hv + 4 * i);
#pragma unroll
  for (int j = 0; j < 32; j++) rv[j] = bias1[j];
#pragma unroll
  for (int i = 0; i < 32; i++) {
    float hi = hv[i];
#pragma unroll
    for (int j = 0; j < 32; j++) rv[j] += hi * root1[i * 32 + j];
  }
#pragma unroll
  for (int i = 0; i < 8; i++) *(float4*)(r1pre + n * 32 + 4 * i) = *(float4*)(rv + 4 * i);
}

// ---------------- edge encoder: ea = edge_attr@We_edge + be_edge -------------
__global__ void k_encode_edges(const float* __restrict__ eattr,
                               const float* __restrict__ We, const float* __restrict__ be,
                               float* __restrict__ ea) {
  int e = blockIdx.x * blockDim.x + threadIdx.x;
  if (e >= NE) return;
  float av[16], ov[32];
#pragma unroll
  for (int i = 0; i < 4; i++) *(float4*)(av + 4 * i) = *(const float4*)(eattr + e * 16 + 4 * i);
#pragma unroll
  for (int j = 0; j < 32; j++) ov[j] = be[j];
#pragma unroll
  for (int k = 0; k < 16; k++) {
    float ak = av[k];
#pragma unroll
    for (int j = 0; j < 32; j++) ov[j] += ak * We[k * 32 + j];
  }
#pragma unroll
  for (int i = 0; i < 8; i++) *(float4*)(ea + e * 32 + 4 * i) = *(float4*)(ov + 4 * i);
}

// ---- node pass 1: h1 = relu(r1pre + gather(msg1)); xl/xr = h1@Wl/Wr + b -----
__global__ void k_node1(const float* __restrict__ r1pre, const float* __restrict__ msgbuf,
                        const int* __restrict__ off, const int* __restrict__ deg,
                        const int* __restrict__ slot,
                        const float* __restrict__ Wl, const float* __restrict__ bl,
                        const float* __restrict__ Wr, const float* __restrict__ br,
                        float* __restrict__ xl, float* __restrict__ xr) {
  int n = blockIdx.x * blockDim.x + threadIdx.x;
  if (n >= NN) return;
  float hv[32];
#pragma unroll
  for (int i = 0; i < 8; i++) *(float4*)(hv + 4 * i) = *(const float4*)(r1pre + n * 32 + 4 * i);
  int o0 = off[n], o1 = o0 + deg[n];
  for (int idx = o0; idx < o1; idx++) {
    int e = slot[idx];
    if (e >= NE) continue;   // self loop: no conv edge
    const float* mp = msgbuf + e * 32;
#pragma unroll
    for (int i = 0; i < 8; i++) {
      float4 mv = *(const float4*)(mp + 4 * i);
      hv[4 * i + 0] += mv.x; hv[4 * i + 1] += mv.y;
      hv[4 * i + 2] += mv.z; hv[4 * i + 3] += mv.w;
    }
  }
#pragma unroll
  for (int j = 0; j < 32; j++) hv[j] = fmaxf(hv[j], 0.f);
  float lv[32], rv[32];
#pragma unroll
  for (int j = 0; j < 32; j++) { lv[j] = bl[j]; rv[j] = br[j]; }
#pragma unroll
  for (int i = 0; i < 32; i++) {
    float hi = hv[i];
#pragma unroll
    for (int j = 0; j < 32; j++) {
      lv[j] += hi * Wl[i * 32 + j];
      rv[j] += hi * Wr[i * 32 + j];
    }
  }
#pragma unroll
  for (int i = 0; i < 8; i++) *(float4*)(xl + n * 32 + 4 * i) = *(float4*)(lv + 4 * i);
#pragma unroll
  for (int i = 0; i < 8; i++) *(float4*)(xr + n * 32 + 4 * i) = *(float4*)(rv + 4 * i);
}

// ---- GAT node pass: segment softmax + weighted gather, fused ---------------
// h2[n] = relu( (sum_e a_e * xl[s_e]) / (sum_e a_e + 1e-16) + bias_gat )
__global__ void k_gat_node(const int* __restrict__ ei,
                           const float* __restrict__ xl, const float* __restrict__ xr,
                           const int* __restrict__ off, const int* __restrict__ deg,
                           const int* __restrict__ slot,
                           const float* __restrict__ att, const float* __restrict__ bias_gat,
                           float* __restrict__ h2) {
  int n = blockIdx.x * blockDim.x + threadIdx.x;
  if (n >= NN) return;
  float xrv[32], attv[32];
#pragma unroll
  for (int i = 0; i < 8; i++) *(float4*)(xrv + 4 * i) = *(const float4*)(xr + n * 32 + 4 * i);
#pragma unroll
  for (int i = 0; i < 8; i++) *(float4*)(attv + 4 * i) = *(const float4*)(att + 4 * i);
  int o0 = off[n], o1 = o0 + deg[n];
  // pass 1: segment max of logits
  float mx[4] = {-1e30f, -1e30f, -1e30f, -1e30f};
  for (int idx = o0; idx < o1; idx++) {
    int e2 = slot[idx];
    int s = (e2 < NE) ? ei[e2] : n;
    const float* xp = xl + s * 32;
#pragma unroll
    for (int hh = 0; hh < 4; hh++) {
      float acc = 0.f;
#pragma unroll
      for (int dg = 0; dg < 8; dg++) {
        float v = xp[hh * 8 + dg] + xrv[hh * 8 + dg];
        v = (v > 0.f) ? v : 0.2f * v;
        acc += v * attv[hh * 8 + dg];
      }
      mx[hh] = fmaxf(mx[hh], acc);
    }
  }
  // pass 2: exp-sum + weighted accumulate
  float accv[32];
#pragma unroll
  for (int j = 0; j < 32; j++) accv[j] = 0.f;
  float den[4] = {0.f, 0.f, 0.f, 0.f};
  for (int idx = o0; idx < o1; idx++) {
    int e2 = slot[idx];
    int s = (e2 < NE) ? ei[e2] : n;
    float xv[32];
#pragma unroll
    for (int i = 0; i < 8; i++) *(float4*)(xv + 4 * i) = *(const float4*)(xl + s * 32 + 4 * i);
#pragma unroll
    for (int hh = 0; hh < 4; hh++) {
      float lg = 0.f;
#pragma unroll
      for (int dg = 0; dg < 8; dg++) {
        float v = xv[hh * 8 + dg] + xrv[hh * 8 + dg];
        v = (v > 0.f) ? v : 0.2f * v;
        lg += v * attv[hh * 8 + dg];
      }
      float a = __expf(lg - mx[hh]);
      den[hh] += a;
#pragma unroll
      for (int dg = 0; dg < 8; dg++) accv[hh * 8 + dg] += a * xv[hh * 8 + dg];
    }
  }
  float hv[32];
#pragma unroll
  for (int hh = 0; hh < 4; hh++) {
    float sc = 1.f / (den[hh] + 1e-16f);
#pragma unroll
    for (int dg = 0; dg < 8; dg++) {
      int j = hh * 8 + dg;
      hv[j] = fmaxf(accv[j] * sc + bias_gat[j], 0.f);
    }
  }
#pragma unroll
  for (int i = 0; i < 8; i++) *(float4*)(h2 + n * 32 + 4 * i) = *(float4*)(hv + 4 * i);
}

// ---- node pass 2: h = relu(h2@root2+bias2 + gather(msg2)); out = h@Wlin+blin
__global__ void k_node2(const float* __restrict__ h2, const float* __restrict__ msgbuf,
                        const int* __restrict__ off, const int* __restrict__ deg,
                        const int* __restrict__ slot,
                        const float* __restrict__ root2, const float* __restrict__ bias2,
                        const float* __restrict__ Wlin, const float* __restrict__ blin,
                        float* __restrict__ out) {
  int n = blockIdx.x * blockDim.x + threadIdx.x;
  if (n >= NN) return;
  float h2v[32], rv[32];
#pragma unroll
  for (int i = 0; i < 8; i++) *(float4*)(h2v + 4 * i) = *(const float4*)(h2 + n * 32 + 4 * i);
#pragma unroll
  for (int j = 0; j < 32; j++) rv[j] = bias2[j];
#pragma unroll
  for (int i = 0; i < 32; i++) {
    float hi = h2v[i];
#pragma unroll
    for (int j = 0; j < 32; j++) rv[j] += hi * root2[i * 32 + j];
  }
  int o0 = off[n], o1 = o0 + deg[n];
  for (int idx = o0; idx < o1; idx++) {
    int e = slot[idx];
    if (e >= NE) continue;
    const float* mp = msgbuf + e * 32;
#pragma unroll
    for (int i = 0; i < 8; i++) {
      float4 mv = *(const float4*)(mp + 4 * i);
      rv[4 * i + 0] += mv.x; rv[4 * i + 1] += mv.y;
      rv[4 * i + 2] += mv.z; rv[4 * i + 3] += mv.w;
    }
  }
#pragma unroll
  for (int j = 0; j < 32; j++) rv[j] = fmaxf(rv[j], 0.f);
  float ov[10];
#pragma unroll
  for (int c = 0; c < 10; c++) ov[c] = blin[c];
#pragma unroll
  for (int j = 0; j < 32; j++) {
    float hj = rv[j];
#pragma unroll
    for (int c = 0; c < 10; c++) ov[c] += hj * Wlin[j * 10 + c];
  }
#pragma unroll
  for (int c = 0; c < 10; c++) out[n * 10 + c] = ov[c];
}

extern "C" void kernel_launch(void* const* d_in, const int* in_sizes, int n_in,
                              void* d_out, int out_size, void* d_ws, size_t ws_size,
                              hipStream_t stream) {
  const float* x         = (const float*)d_in[0];
  const float* edge_attr = (const float*)d_in[1];
  const int*   ei        = (const int*)d_in[2];   // [2,E]: src = ei, dst = ei+NE
  const float* We_node   = (const float*)d_in[3];
  const float* be_node   = (const float*)d_in[4];
  const float* We_edge   = (const float*)d_in[5];
  const float* be_edge   = (const float*)d_in[6];
  const float* W1_nn     = (const float*)d_in[7];
  const float* b1_nn     = (const float*)d_in[8];
  const float* root1     = (const float*)d_in[9];
  const float* bias1     = (const float*)d_in[10];
  const float* Wl        = (const float*)d_in[11];
  const float* bl        = (const float*)d_in[12];
  const float* Wr        = (const float*)d_in[13];
  const float* br        = (const float*)d_in[14];
  const float* att       = (const float*)d_in[15];
  const float* bias_gat  = (const float*)d_in[16];
  const float* W2_nn     = (const float*)d_in[17];
  const float* b2_nn     = (const float*)d_in[18];
  const float* root2     = (const float*)d_in[19];
  const float* bias2     = (const float*)d_in[20];
  const float* Wlin      = (const float*)d_in[21];
  const float* blin      = (const float*)d_in[22];
  float* out = (float*)d_out;

  float* ws = (float*)d_ws;
  float* h0h2  = ws;                 // NN*32 (h0, later h2)
  float* ea    = h0h2 + NN * 32;     // NE*32
  float* r1pre = ea + NE * 32;       // NN*32
  float* xl    = r1pre + NN * 32;    // NN*32
  float* xr    = xl + NN * 32;       // NN*32
  float* msgbuf = xr + NN * 32;      // NE*32 (reused conv1/conv2)
  float* fend  = msgbuf + NE * 32;
  __hip_bfloat16* Bswz1 = (__hip_bfloat16*)fend;            // 33792 bf16
  __hip_bfloat16* Bswz2 = (__hip_bfloat16*)(fend + 17000);  // 33792 bf16
  int* deg    = (int*)(fend + 34000);   // NN
  int* off    = deg + NN;               // NN
  int* cursor = off + NN;               // NN
  int* slot   = cursor + NN;            // NE2

  const int B = 256;
  k_csr_init<<<(NN + B - 1) / B, B, 0, stream>>>(deg);
  k_csr_count<<<(NE + B - 1) / B, B, 0, stream>>>(ei, deg);
  k_csr_scan<<<1, 1024, 0, stream>>>(deg, off, cursor);
  k_csr_fill<<<(NE2 + B - 1) / B, B, 0, stream>>>(ei, cursor, slot);
  k_pack_w<<<132, B, 0, stream>>>(W1_nn, b1_nn, Bswz1);
  k_pack_w<<<132, B, 0, stream>>>(W2_nn, b2_nn, Bswz2);
  k_encode_nodes<<<(NN + B - 1) / B, B, 0, stream>>>(x, We_node, be_node, root1, bias1, h0h2, r1pre);
  k_encode_edges<<<(NE + B - 1) / B, B, 0, stream>>>(edge_attr, We_edge, be_edge, ea);
  k_nnconv_mfma<<<512, B, 65536, stream>>>(h0h2, ea, Bswz1, ei, msgbuf);
  k_node1<<<(NN + B - 1) / B, B, 0, stream>>>(r1pre, msgbuf, off, deg, slot, Wl, bl, Wr, br, xl, xr);
  k_gat_node<<<(NN + B - 1) / B, B, 0, stream>>>(ei, xl, xr, off, deg, slot, att, bias_gat, h0h2);
  k_nnconv_mfma<<<512, B, 65536, stream>>>(h0h2, ea, Bswz2, ei, msgbuf);
  k_node2<<<(NN + B - 1) / B, B, 0, stream>>>(h0h2, msgbuf, off, deg, slot, root2, bias2, Wlin, blin, out);
}

// Round 4
// 174.587 us; speedup vs baseline: 16.1735x; 1.3440x over previous
//
#include <hip/hip_runtime.h>
#include <hip/hip_bf16.h>
#include <math.h>

#define NN 25000
#define NE 100000
#define NTILES (NE / 16)   // 6250 edge tiles of 16
#define NBN 98             // ceil(NN/256)
#define NBE 391            // ceil(NE/256)
#define NBP 264            // ceil(2*33792/256)
#define NBC 391            // ceil(NE/256)

typedef __attribute__((ext_vector_type(8))) short short8;
typedef __attribute__((ext_vector_type(4))) float f32x4;

static __device__ __forceinline__ short f2bf(float f) {
  union { __hip_bfloat16 h; short s; } cv;
  cv.h = __float2bfloat16(f);
  return cv.s;
}

// ==== fused prep: node encoder | edge encoder | W-pack x2 | degree count ====
__global__ void __launch_bounds__(256) k_prep(
    const float* __restrict__ x, const float* __restrict__ eattr,
    const int* __restrict__ ei,
    const float* __restrict__ We_node, const float* __restrict__ be_node,
    const float* __restrict__ We_edge, const float* __restrict__ be_edge,
    const float* __restrict__ root1, const float* __restrict__ bias1,
    const float* __restrict__ W1, const float* __restrict__ b1,
    const float* __restrict__ W2, const float* __restrict__ b2,
    float* __restrict__ h0, float* __restrict__ r1pre, float* __restrict__ ea,
    __hip_bfloat16* __restrict__ Bswz1, __hip_bfloat16* __restrict__ Bswz2,
    int* __restrict__ deg) {
  int b = blockIdx.x;
  int tid = threadIdx.x;
  if (b < NBN) {
    // ---- node encoder: h0 = x@We+be ; r1pre = h0@root1+bias1 ----
    int n = b * 256 + tid;
    if (n >= NN) return;
    float xv[32], hv[32], rv[32];
#pragma unroll
    for (int i = 0; i < 8; i++) *(float4*)(xv + 4 * i) = *(const float4*)(x + n * 32 + 4 * i);
#pragma unroll
    for (int j = 0; j < 32; j++) hv[j] = be_node[j];
#pragma unroll
    for (int i = 0; i < 32; i++) {
      float xi = xv[i];
#pragma unroll
      for (int j = 0; j < 32; j++) hv[j] += xi * We_node[i * 32 + j];
    }
#pragma unroll
    for (int i = 0; i < 8; i++) *(float4*)(h0 + n * 32 + 4 * i) = *(float4*)(hv + 4 * i);
#pragma unroll
    for (int j = 0; j < 32; j++) rv[j] = bias1[j];
#pragma unroll
    for (int i = 0; i < 32; i++) {
      float hi = hv[i];
#pragma unroll
      for (int j = 0; j < 32; j++) rv[j] += hi * root1[i * 32 + j];
    }
#pragma unroll
    for (int i = 0; i < 8; i++) *(float4*)(r1pre + n * 32 + 4 * i) = *(float4*)(rv + 4 * i);
  } else if (b < NBN + NBE) {
    // ---- edge encoder: ea = edge_attr@We_edge + be_edge ----
    int e = (b - NBN) * 256 + tid;
    if (e >= NE) return;
    float av[16], ov[32];
#pragma unroll
    for (int i = 0; i < 4; i++) *(float4*)(av + 4 * i) = *(const float4*)(eattr + e * 16 + 4 * i);
#pragma unroll
    for (int j = 0; j < 32; j++) ov[j] = be_edge[j];
#pragma unroll
    for (int k = 0; k < 16; k++) {
      float ak = av[k];
#pragma unroll
      for (int j = 0; j < 32; j++) ov[j] += ak * We_edge[k * 32 + j];
    }
#pragma unroll
    for (int i = 0; i < 8; i++) *(float4*)(ea + e * 32 + 4 * i) = *(float4*)(ov + 4 * i);
  } else if (b < NBN + NBE + NBP) {
    // ---- pack W_nn (+bias row) into MFMA B-fragment order, both convs ----
    int idx = (b - NBN - NBE) * 256 + tid;
    if (idx >= 2 * 33792) return;
    int sel = idx >= 33792;
    int r = idx - sel * 33792;
    int j = r & 7;
    int l = (r >> 3) & 63;
    int nt = (r >> 9) & 1;
    int t = r >> 10;
    int i = 8 * (l >> 4) + j;
    int o = nt * 16 + (l & 15);
    const float* W = sel ? W2 : W1;
    const float* bb = sel ? b2 : b1;
    float v = (t < 32) ? W[t * 1024 + i * 32 + o] : bb[i * 32 + o];
    (sel ? Bswz2 : Bswz1)[r] = __float2bfloat16(v);
  } else {
    // ---- degree count (real edges only; self loops handled analytically) ----
    int e = (b - NBN - NBE - NBP) * 256 + tid;
    if (e < NE) atomicAdd(&deg[ei[NE + e]], 1);
  }
}

// ==== scan stage 1: per-block sums of deg ====
__global__ void __launch_bounds__(256) k_scan1(const int* __restrict__ deg,
                                               int* __restrict__ bsum) {
  __shared__ int s[256];
  int tid = threadIdx.x;
  int n = blockIdx.x * 256 + tid;
  s[tid] = (n < NN) ? deg[n] : 0;
  __syncthreads();
  for (int d = 128; d > 0; d >>= 1) {
    if (tid < d) s[tid] += s[tid + d];
    __syncthreads();
  }
  if (tid == 0) bsum[blockIdx.x] = s[0];
}

// ==== scan stage 2: block-local exclusive scan + bsum prefix -> off/cursor ===
__global__ void __launch_bounds__(256) k_scan3(const int* __restrict__ deg,
                                               const int* __restrict__ bsum,
                                               int* __restrict__ off,
                                               int* __restrict__ cursor) {
  __shared__ int sb[128];
  __shared__ int s[256];
  int tid = threadIdx.x;
  if (tid < 128) sb[tid] = (tid < NBN) ? bsum[tid] : 0;
  int n = blockIdx.x * 256 + tid;
  int v = (n < NN) ? deg[n] : 0;
  s[tid] = v;
  __syncthreads();
  for (int d = 1; d < 128; d <<= 1) {
    int t = 0;
    if (tid < 128 && tid >= d) t = sb[tid - d];
    __syncthreads();
    if (tid < 128) sb[tid] += t;
    __syncthreads();
  }
  for (int d = 1; d < 256; d <<= 1) {
    int t = (tid >= d) ? s[tid - d] : 0;
    __syncthreads();
    s[tid] += t;
    __syncthreads();
  }
  int base = (blockIdx.x > 0) ? sb[blockIdx.x - 1] : 0;
  int excl = s[tid] - v + base;
  if (n < NN) { off[n] = excl; cursor[n] = excl; }
}

// ==== CSR fill (real edges only) ====
__global__ void k_csr_fill(const int* __restrict__ ei, int* __restrict__ cursor,
                           int* __restrict__ slot) {
  int e = blockIdx.x * blockDim.x + threadIdx.x;
  if (e >= NE) return;
  int d = ei[NE + e];
  int p = atomicAdd(&cursor[d], 1);
  slot[p] = e;
}

// ---- NNConv as MFMA GEMM; epilogue = coalesced stores to msgbuf -------------
__global__ void __launch_bounds__(256) k_nnconv_mfma(
    const float* __restrict__ hin, const float* __restrict__ ea,
    const __hip_bfloat16* __restrict__ Bswz, const int* __restrict__ ei,
    float* __restrict__ msgbuf) {
  extern __shared__ short8 bsh[];   // 32 steps * 2 ntiles * 64 lanes = 64 KB
  int tid = threadIdx.x;
  {
    uint4* s4 = (uint4*)bsh;
    const uint4* g4 = (const uint4*)Bswz;
#pragma unroll
    for (int it = 0; it < 16; it++) s4[tid + 256 * it] = g4[tid + 256 * it];
  }
  __syncthreads();

  int wid = tid >> 6;
  int lane = tid & 63;
  int lrow = lane & 15;        // A row / C col
  int lk8 = (lane >> 4) * 8;   // k-offset of this lane's 8 A elems

  for (int tile = blockIdx.x * 4 + wid; tile < NTILES; tile += gridDim.x * 4) {
    int e0 = tile * 16;
    int e = e0 + lrow;
    int src = ei[e];
    float hf[8];
    *(float4*)(hf)     = *(const float4*)(hin + src * 32 + lk8);
    *(float4*)(hf + 4) = *(const float4*)(hin + src * 32 + lk8 + 4);
    float eav[32];
#pragma unroll
    for (int c = 0; c < 8; c++)
      *(float4*)(eav + 4 * c) = *(const float4*)(ea + e * 32 + 4 * c);

    f32x4 a00 = {0.f, 0.f, 0.f, 0.f}, a01 = a00, a10 = a00, a11 = a00;
#pragma unroll
    for (int t = 0; t < 32; t++) {
      float et = eav[t];
      short8 af;
#pragma unroll
      for (int j = 0; j < 8; j++) af[j] = f2bf(et * hf[j]);
      short8 b0 = bsh[(t * 2 + 0) * 64 + lane];
      short8 b1 = bsh[(t * 2 + 1) * 64 + lane];
      if (t & 1) {
        a01 = __builtin_amdgcn_mfma_f32_16x16x32_bf16(af, b0, a01, 0, 0, 0);
        a11 = __builtin_amdgcn_mfma_f32_16x16x32_bf16(af, b1, a11, 0, 0, 0);
      } else {
        a00 = __builtin_amdgcn_mfma_f32_16x16x32_bf16(af, b0, a00, 0, 0, 0);
        a10 = __builtin_amdgcn_mfma_f32_16x16x32_bf16(af, b1, a10, 0, 0, 0);
      }
    }
    // bias K-step (t=32): A = h itself, B from global (L2-cached)
    {
      short8 af;
#pragma unroll
      for (int j = 0; j < 8; j++) af[j] = f2bf(hf[j]);
      const short8* gb = (const short8*)Bswz;
      short8 b0 = gb[(32 * 2 + 0) * 64 + lane];
      short8 b1 = gb[(32 * 2 + 1) * 64 + lane];
      a00 = __builtin_amdgcn_mfma_f32_16x16x32_bf16(af, b0, a00, 0, 0, 0);
      a10 = __builtin_amdgcn_mfma_f32_16x16x32_bf16(af, b1, a10, 0, 0, 0);
    }
    f32x4 c0 = a00 + a01;
    f32x4 c1 = a10 + a11;
    int r0 = (lane >> 4) * 4;
#pragma unroll
    for (int r = 0; r < 4; r++) {
      float* mp = msgbuf + (e0 + r0 + r) * 32 + lrow;
      mp[0]  = c0[r];
      mp[16] = c1[r];
    }
  }
}

// ---- node pass 1: h1 = relu(r1pre + gather(msg1)); xl/xr = h1@Wl/Wr + b -----
__global__ void k_node1(const float* __restrict__ r1pre, const float* __restrict__ msgbuf,
                        const int* __restrict__ off, const int* __restrict__ deg,
                        const int* __restrict__ slot,
                        const float* __restrict__ Wl, const float* __restrict__ bl,
                        const float* __restrict__ Wr, const float* __restrict__ br,
                        float* __restrict__ xl, float* __restrict__ xr) {
  int n = blockIdx.x * blockDim.x + threadIdx.x;
  if (n >= NN) return;
  float hv[32];
#pragma unroll
  for (int i = 0; i < 8; i++) *(float4*)(hv + 4 * i) = *(const float4*)(r1pre + n * 32 + 4 * i);
  int o0 = off[n], o1 = o0 + deg[n];
  for (int idx = o0; idx < o1; idx++) {
    int e = slot[idx];
    const float* mp = msgbuf + e * 32;
#pragma unroll
    for (int i = 0; i < 8; i++) {
      float4 mv = *(const float4*)(mp + 4 * i);
      hv[4 * i + 0] += mv.x; hv[4 * i + 1] += mv.y;
      hv[4 * i + 2] += mv.z; hv[4 * i + 3] += mv.w;
    }
  }
#pragma unroll
  for (int j = 0; j < 32; j++) hv[j] = fmaxf(hv[j], 0.f);
  float lv[32], rv[32];
#pragma unroll
  for (int j = 0; j < 32; j++) { lv[j] = bl[j]; rv[j] = br[j]; }
#pragma unroll
  for (int i = 0; i < 32; i++) {
    float hi = hv[i];
#pragma unroll
    for (int j = 0; j < 32; j++) {
      lv[j] += hi * Wl[i * 32 + j];
      rv[j] += hi * Wr[i * 32 + j];
    }
  }
#pragma unroll
  for (int i = 0; i < 8; i++) *(float4*)(xl + n * 32 + 4 * i) = *(float4*)(lv + 4 * i);
#pragma unroll
  for (int i = 0; i < 8; i++) *(float4*)(xr + n * 32 + 4 * i) = *(float4*)(rv + 4 * i);
}

// ---- GAT node pass: segment softmax + weighted gather (self-loop inline) ----
__global__ void k_gat_node(const int* __restrict__ ei,
                           const float* __restrict__ xl, const float* __restrict__ xr,
                           const int* __restrict__ off, const int* __restrict__ deg,
                           const int* __restrict__ slot,
                           const float* __restrict__ att, const float* __restrict__ bias_gat,
                           float* __restrict__ h2) {
  int n = blockIdx.x * blockDim.x + threadIdx.x;
  if (n >= NN) return;
  float xrv[32], attv[32], xself[32];
#pragma unroll
  for (int i = 0; i < 8; i++) *(float4*)(xrv + 4 * i) = *(const float4*)(xr + n * 32 + 4 * i);
#pragma unroll
  for (int i = 0; i < 8; i++) *(float4*)(attv + 4 * i) = *(const float4*)(att + 4 * i);
#pragma unroll
  for (int i = 0; i < 8; i++) *(float4*)(xself + 4 * i) = *(const float4*)(xl + n * 32 + 4 * i);
  int o0 = off[n], o1 = o0 + deg[n];
  // self-loop logits seed the max
  float mx[4];
#pragma unroll
  for (int hh = 0; hh < 4; hh++) {
    float acc = 0.f;
#pragma unroll
    for (int dg = 0; dg < 8; dg++) {
      float v = xself[hh * 8 + dg] + xrv[hh * 8 + dg];
      v = (v > 0.f) ? v : 0.2f * v;
      acc += v * attv[hh * 8 + dg];
    }
    mx[hh] = acc;
  }
  // pass 1: segment max over real edges
  for (int idx = o0; idx < o1; idx++) {
    int s = ei[slot[idx]];
    const float* xp = xl + s * 32;
#pragma unroll
    for (int hh = 0; hh < 4; hh++) {
      float acc = 0.f;
#pragma unroll
      for (int dg = 0; dg < 8; dg++) {
        float v = xp[hh * 8 + dg] + xrv[hh * 8 + dg];
        v = (v > 0.f) ? v : 0.2f * v;
        acc += v * attv[hh * 8 + dg];
      }
      mx[hh] = fmaxf(mx[hh], acc);
    }
  }
  // pass 2: exp-sum + weighted accumulate (self loop first)
  float accv[32];
  float den[4];
#pragma unroll
  for (int hh = 0; hh < 4; hh++) {
    float lg = 0.f;
#pragma unroll
    for (int dg = 0; dg < 8; dg++) {
      float v = xself[hh * 8 + dg] + xrv[hh * 8 + dg];
      v = (v > 0.f) ? v : 0.2f * v;
      lg += v * attv[hh * 8 + dg];
    }
    float a = __expf(lg - mx[hh]);
    den[hh] = a;
#pragma unroll
    for (int dg = 0; dg < 8; dg++) accv[hh * 8 + dg] = a * xself[hh * 8 + dg];
  }
  for (int idx = o0; idx < o1; idx++) {
    int s = ei[slot[idx]];
    float xv[32];
#pragma unroll
    for (int i = 0; i < 8; i++) *(float4*)(xv + 4 * i) = *(const float4*)(xl + s * 32 + 4 * i);
#pragma unroll
    for (int hh = 0; hh < 4; hh++) {
      float lg = 0.f;
#pragma unroll
      for (int dg = 0; dg < 8; dg++) {
        float v = xv[hh * 8 + dg] + xrv[hh * 8 + dg];
        v = (v > 0.f) ? v : 0.2f * v;
        lg += v * attv[hh * 8 + dg];
      }
      float a = __expf(lg - mx[hh]);
      den[hh] += a;
#pragma unroll
      for (int dg = 0; dg < 8; dg++) accv[hh * 8 + dg] += a * xv[hh * 8 + dg];
    }
  }
  float hv[32];
#pragma unroll
  for (int hh = 0; hh < 4; hh++) {
    float sc = 1.f / (den[hh] + 1e-16f);
#pragma unroll
    for (int dg = 0; dg < 8; dg++) {
      int j = hh * 8 + dg;
      hv[j] = fmaxf(accv[j] * sc + bias_gat[j], 0.f);
    }
  }
#pragma unroll
  for (int i = 0; i < 8; i++) *(float4*)(h2 + n * 32 + 4 * i) = *(float4*)(hv + 4 * i);
}

// ---- node pass 2: h = relu(h2@root2+bias2 + gather(msg2)); out = h@Wlin+blin
__global__ void k_node2(const float* __restrict__ h2, const float* __restrict__ msgbuf,
                        const int* __restrict__ off, const int* __restrict__ deg,
                        const int* __restrict__ slot,
                        const float* __restrict__ root2, const float* __restrict__ bias2,
                        const float* __restrict__ Wlin, const float* __restrict__ blin,
                        float* __restrict__ out) {
  int n = blockIdx.x * blockDim.x + threadIdx.x;
  if (n >= NN) return;
  float h2v[32], rv[32];
#pragma unroll
  for (int i = 0; i < 8; i++) *(float4*)(h2v + 4 * i) = *(const float4*)(h2 + n * 32 + 4 * i);
#pragma unroll
  for (int j = 0; j < 32; j++) rv[j] = bias2[j];
#pragma unroll
  for (int i = 0; i < 32; i++) {
    float hi = h2v[i];
#pragma unroll
    for (int j = 0; j < 32; j++) rv[j] += hi * root2[i * 32 + j];
  }
  int o0 = off[n], o1 = o0 + deg[n];
  for (int idx = o0; idx < o1; idx++) {
    int e = slot[idx];
    const float* mp = msgbuf + e * 32;
#pragma unroll
    for (int i = 0; i < 8; i++) {
      float4 mv = *(const float4*)(mp + 4 * i);
      rv[4 * i + 0] += mv.x; rv[4 * i + 1] += mv.y;
      rv[4 * i + 2] += mv.z; rv[4 * i + 3] += mv.w;
    }
  }
#pragma unroll
  for (int j = 0; j < 32; j++) rv[j] = fmaxf(rv[j], 0.f);
  float ov[10];
#pragma unroll
  for (int c = 0; c < 10; c++) ov[c] = blin[c];
#pragma unroll
  for (int j = 0; j < 32; j++) {
    float hj = rv[j];
#pragma unroll
    for (int c = 0; c < 10; c++) ov[c] += hj * Wlin[j * 10 + c];
  }
#pragma unroll
  for (int c = 0; c < 10; c++) out[n * 10 + c] = ov[c];
}

extern "C" void kernel_launch(void* const* d_in, const int* in_sizes, int n_in,
                              void* d_out, int out_size, void* d_ws, size_t ws_size,
                              hipStream_t stream) {
  const float* x         = (const float*)d_in[0];
  const float* edge_attr = (const float*)d_in[1];
  const int*   ei        = (const int*)d_in[2];   // [2,E]: src = ei, dst = ei+NE
  const float* We_node   = (const float*)d_in[3];
  const float* be_node   = (const float*)d_in[4];
  const float* We_edge   = (const float*)d_in[5];
  const float* be_edge   = (const float*)d_in[6];
  const float* W1_nn     = (const float*)d_in[7];
  const float* b1_nn     = (const float*)d_in[8];
  const float* root1     = (const float*)d_in[9];
  const float* bias1     = (const float*)d_in[10];
  const float* Wl        = (const float*)d_in[11];
  const float* bl        = (const float*)d_in[12];
  const float* Wr        = (const float*)d_in[13];
  const float* br        = (const float*)d_in[14];
  const float* att       = (const float*)d_in[15];
  const float* bias_gat  = (const float*)d_in[16];
  const float* W2_nn     = (const float*)d_in[17];
  const float* b2_nn     = (const float*)d_in[18];
  const float* root2     = (const float*)d_in[19];
  const float* bias2     = (const float*)d_in[20];
  const float* Wlin      = (const float*)d_in[21];
  const float* blin      = (const float*)d_in[22];
  float* out = (float*)d_out;

  float* ws = (float*)d_ws;
  float* h0h2  = ws;                 // NN*32 (h0, later h2)
  float* ea    = h0h2 + NN * 32;     // NE*32
  float* r1pre = ea + NE * 32;       // NN*32
  float* xl    = r1pre + NN * 32;    // NN*32
  float* xr    = xl + NN * 32;       // NN*32
  float* msgbuf = xr + NN * 32;      // NE*32 (reused conv1/conv2)
  float* fend  = msgbuf + NE * 32;
  __hip_bfloat16* Bswz1 = (__hip_bfloat16*)fend;            // 33792 bf16
  __hip_bfloat16* Bswz2 = (__hip_bfloat16*)(fend + 17000);  // 33792 bf16
  int* deg    = (int*)(fend + 34000);   // NN
  int* off    = deg + NN;               // NN
  int* cursor = off + NN;               // NN
  int* bsum   = cursor + NN;            // 128
  int* slot   = bsum + 128;             // NE

  const int B = 256;
  hipMemsetAsync(deg, 0, NN * sizeof(int), stream);
  k_prep<<<NBN + NBE + NBP + NBC, B, 0, stream>>>(
      x, edge_attr, ei, We_node, be_node, We_edge, be_edge, root1, bias1,
      W1_nn, b1_nn, W2_nn, b2_nn, h0h2, r1pre, ea, Bswz1, Bswz2, deg);
  k_scan1<<<NBN, B, 0, stream>>>(deg, bsum);
  k_scan3<<<NBN, B, 0, stream>>>(deg, bsum, off, cursor);
  k_csr_fill<<<(NE + B - 1) / B, B, 0, stream>>>(ei, cursor, slot);
  k_nnconv_mfma<<<512, B, 65536, stream>>>(h0h2, ea, Bswz1, ei, msgbuf);
  k_node1<<<(NN + B - 1) / B, B, 0, stream>>>(r1pre, msgbuf, off, deg, slot, Wl, bl, Wr, br, xl, xr);
  k_gat_node<<<(NN + B - 1) / B, B, 0, stream>>>(ei, xl, xr, off, deg, slot, att, bias_gat, h0h2);
  k_nnconv_mfma<<<512, B, 65536, stream>>>(h0h2, ea, Bswz2, ei, msgbuf);
  k_node2<<<(NN + B - 1) / B, B, 0, stream>>>(h0h2, msgbuf, off, deg, slot, root2, bias2, Wlin, blin, out);
}

// Round 5
// 148.720 us; speedup vs baseline: 18.9865x; 1.1739x over previous
//
#include <hip/hip_runtime.h>
#include <hip/hip_bf16.h>
#include <math.h>

#define NN 25000
#define NE 100000
#define NTILES (NE / 16)   // 6250 edge tiles of 16
#define NBN 98             // ceil(NN/256)
#define NBE 391            // ceil(NE/256)
#define NBP 264            // ceil(2*33792/256)
#define NBC 391            // ceil(NE/256)

typedef __attribute__((ext_vector_type(8))) short short8;
typedef __attribute__((ext_vector_type(4))) float f32x4;

static __device__ __forceinline__ short f2bf(float f) {
  union { __hip_bfloat16 h; short s; } cv;
  cv.h = __float2bfloat16(f);
  return cv.s;
}

// ==== zero deg (replaces 43us rocclr fill) ====
__global__ void __launch_bounds__(256) k_zero(int* __restrict__ deg) {
  int n = blockIdx.x * 256 + threadIdx.x;
  if (n < NN) deg[n] = 0;
}

// ==== fused prep: node encoder | edge encoder | W-pack x2 | degree count ====
__global__ void __launch_bounds__(256) k_prep(
    const float* __restrict__ x, const float* __restrict__ eattr,
    const int* __restrict__ ei,
    const float* __restrict__ We_node, const float* __restrict__ be_node,
    const float* __restrict__ We_edge, const float* __restrict__ be_edge,
    const float* __restrict__ root1, const float* __restrict__ bias1,
    const float* __restrict__ W1, const float* __restrict__ b1,
    const float* __restrict__ W2, const float* __restrict__ b2,
    float* __restrict__ h0, float* __restrict__ r1pre, float* __restrict__ ea,
    __hip_bfloat16* __restrict__ Bswz1, __hip_bfloat16* __restrict__ Bswz2,
    int* __restrict__ deg) {
  int b = blockIdx.x;
  int tid = threadIdx.x;
  if (b < NBN) {
    int n = b * 256 + tid;
    if (n >= NN) return;
    float xv[32], hv[32], rv[32];
#pragma unroll
    for (int i = 0; i < 8; i++) *(float4*)(xv + 4 * i) = *(const float4*)(x + n * 32 + 4 * i);
#pragma unroll
    for (int j = 0; j < 32; j++) hv[j] = be_node[j];
#pragma unroll
    for (int i = 0; i < 32; i++) {
      float xi = xv[i];
#pragma unroll
      for (int j = 0; j < 32; j++) hv[j] += xi * We_node[i * 32 + j];
    }
#pragma unroll
    for (int i = 0; i < 8; i++) *(float4*)(h0 + n * 32 + 4 * i) = *(float4*)(hv + 4 * i);
#pragma unroll
    for (int j = 0; j < 32; j++) rv[j] = bias1[j];
#pragma unroll
    for (int i = 0; i < 32; i++) {
      float hi = hv[i];
#pragma unroll
      for (int j = 0; j < 32; j++) rv[j] += hi * root1[i * 32 + j];
    }
#pragma unroll
    for (int i = 0; i < 8; i++) *(float4*)(r1pre + n * 32 + 4 * i) = *(float4*)(rv + 4 * i);
  } else if (b < NBN + NBE) {
    int e = (b - NBN) * 256 + tid;
    if (e >= NE) return;
    float av[16], ov[32];
#pragma unroll
    for (int i = 0; i < 4; i++) *(float4*)(av + 4 * i) = *(const float4*)(eattr + e * 16 + 4 * i);
#pragma unroll
    for (int j = 0; j < 32; j++) ov[j] = be_edge[j];
#pragma unroll
    for (int k = 0; k < 16; k++) {
      float ak = av[k];
#pragma unroll
      for (int j = 0; j < 32; j++) ov[j] += ak * We_edge[k * 32 + j];
    }
#pragma unroll
    for (int i = 0; i < 8; i++) *(float4*)(ea + e * 32 + 4 * i) = *(float4*)(ov + 4 * i);
  } else if (b < NBN + NBE + NBP) {
    int idx = (b - NBN - NBE) * 256 + tid;
    if (idx >= 2 * 33792) return;
    int sel = idx >= 33792;
    int r = idx - sel * 33792;
    int j = r & 7;
    int l = (r >> 3) & 63;
    int nt = (r >> 9) & 1;
    int t = r >> 10;
    int i = 8 * (l >> 4) + j;
    int o = nt * 16 + (l & 15);
    const float* W = sel ? W2 : W1;
    const float* bb = sel ? b2 : b1;
    float v = (t < 32) ? W[t * 1024 + i * 32 + o] : bb[i * 32 + o];
    (sel ? Bswz2 : Bswz1)[r] = __float2bfloat16(v);
  } else {
    int e = (b - NBN - NBE - NBP) * 256 + tid;
    if (e < NE) atomicAdd(&deg[ei[NE + e]], 1);
  }
}

// ==== scan stage 1: per-block sums of deg ====
__global__ void __launch_bounds__(256) k_scan1(const int* __restrict__ deg,
                                               int* __restrict__ bsum) {
  __shared__ int s[256];
  int tid = threadIdx.x;
  int n = blockIdx.x * 256 + tid;
  s[tid] = (n < NN) ? deg[n] : 0;
  __syncthreads();
  for (int d = 128; d > 0; d >>= 1) {
    if (tid < d) s[tid] += s[tid + d];
    __syncthreads();
  }
  if (tid == 0) bsum[blockIdx.x] = s[0];
}

// ==== scan stage 2: block-local exclusive scan + bsum prefix -> off/cursor ===
__global__ void __launch_bounds__(256) k_scan3(const int* __restrict__ deg,
                                               const int* __restrict__ bsum,
                                               int* __restrict__ off,
                                               int* __restrict__ cursor) {
  __shared__ int sb[128];
  __shared__ int s[256];
  int tid = threadIdx.x;
  if (tid < 128) sb[tid] = (tid < NBN) ? bsum[tid] : 0;
  int n = blockIdx.x * 256 + tid;
  int v = (n < NN) ? deg[n] : 0;
  s[tid] = v;
  __syncthreads();
  for (int d = 1; d < 128; d <<= 1) {
    int t = 0;
    if (tid < 128 && tid >= d) t = sb[tid - d];
    __syncthreads();
    if (tid < 128) sb[tid] += t;
    __syncthreads();
  }
  for (int d = 1; d < 256; d <<= 1) {
    int t = (tid >= d) ? s[tid - d] : 0;
    __syncthreads();
    s[tid] += t;
    __syncthreads();
  }
  int base = (blockIdx.x > 0) ? sb[blockIdx.x - 1] : 0;
  int excl = s[tid] - v + base;
  if (n < NN) { off[n] = excl; cursor[n] = excl; }
}

// ==== CSR fill (real edges only) ====
__global__ void k_csr_fill(const int* __restrict__ ei, int* __restrict__ cursor,
                           int* __restrict__ slot) {
  int e = blockIdx.x * blockDim.x + threadIdx.x;
  if (e >= NE) return;
  int d = ei[NE + e];
  int p = atomicAdd(&cursor[d], 1);
  slot[p] = e;
}

// ---- NNConv as MFMA GEMM; epilogue = coalesced stores to msgbuf -------------
__global__ void __launch_bounds__(256) k_nnconv_mfma(
    const float* __restrict__ hin, const float* __restrict__ ea,
    const __hip_bfloat16* __restrict__ Bswz, const int* __restrict__ ei,
    float* __restrict__ msgbuf) {
  extern __shared__ short8 bsh[];   // 32 steps * 2 ntiles * 64 lanes = 64 KB
  int tid = threadIdx.x;
  {
    uint4* s4 = (uint4*)bsh;
    const uint4* g4 = (const uint4*)Bswz;
#pragma unroll
    for (int it = 0; it < 16; it++) s4[tid + 256 * it] = g4[tid + 256 * it];
  }
  __syncthreads();

  int wid = tid >> 6;
  int lane = tid & 63;
  int lrow = lane & 15;        // A row / C col
  int lk8 = (lane >> 4) * 8;   // k-offset of this lane's 8 A elems

  for (int tile = blockIdx.x * 4 + wid; tile < NTILES; tile += gridDim.x * 4) {
    int e0 = tile * 16;
    int e = e0 + lrow;
    int src = ei[e];
    float hf[8];
    *(float4*)(hf)     = *(const float4*)(hin + src * 32 + lk8);
    *(float4*)(hf + 4) = *(const float4*)(hin + src * 32 + lk8 + 4);
    float eav[32];
#pragma unroll
    for (int c = 0; c < 8; c++)
      *(float4*)(eav + 4 * c) = *(const float4*)(ea + e * 32 + 4 * c);

    f32x4 a00 = {0.f, 0.f, 0.f, 0.f}, a01 = a00, a10 = a00, a11 = a00;
#pragma unroll
    for (int t = 0; t < 32; t++) {
      float et = eav[t];
      short8 af;
#pragma unroll
      for (int j = 0; j < 8; j++) af[j] = f2bf(et * hf[j]);
      short8 b0 = bsh[(t * 2 + 0) * 64 + lane];
      short8 b1 = bsh[(t * 2 + 1) * 64 + lane];
      if (t & 1) {
        a01 = __builtin_amdgcn_mfma_f32_16x16x32_bf16(af, b0, a01, 0, 0, 0);
        a11 = __builtin_amdgcn_mfma_f32_16x16x32_bf16(af, b1, a11, 0, 0, 0);
      } else {
        a00 = __builtin_amdgcn_mfma_f32_16x16x32_bf16(af, b0, a00, 0, 0, 0);
        a10 = __builtin_amdgcn_mfma_f32_16x16x32_bf16(af, b1, a10, 0, 0, 0);
      }
    }
    {
      short8 af;
#pragma unroll
      for (int j = 0; j < 8; j++) af[j] = f2bf(hf[j]);
      const short8* gb = (const short8*)Bswz;
      short8 b0 = gb[(32 * 2 + 0) * 64 + lane];
      short8 b1 = gb[(32 * 2 + 1) * 64 + lane];
      a00 = __builtin_amdgcn_mfma_f32_16x16x32_bf16(af, b0, a00, 0, 0, 0);
      a10 = __builtin_amdgcn_mfma_f32_16x16x32_bf16(af, b1, a10, 0, 0, 0);
    }
    f32x4 c0 = a00 + a01;
    f32x4 c1 = a10 + a11;
    int r0 = (lane >> 4) * 4;
#pragma unroll
    for (int r = 0; r < 4; r++) {
      float* mp = msgbuf + (e0 + r0 + r) * 32 + lrow;
      mp[0]  = c0[r];
      mp[16] = c1[r];
    }
  }
}

// ---- node pass 1 (2 threads/node): gather half, pair-exchange, GEMM ---------
// half 0 -> xl row, half 1 -> xr row
__global__ void __launch_bounds__(256) k_node1(
    const float* __restrict__ r1pre, const float* __restrict__ msgbuf,
    const int* __restrict__ off, const int* __restrict__ deg,
    const int* __restrict__ slot,
    const float* __restrict__ Wl, const float* __restrict__ bl,
    const float* __restrict__ Wr, const float* __restrict__ br,
    float* __restrict__ xl, float* __restrict__ xr) {
  int t = blockIdx.x * blockDim.x + threadIdx.x;
  if (t >= 2 * NN) return;
  int n = t >> 1, half = t & 1;
  int c0 = half * 16;
  float hv[16];
  const float* rp = r1pre + n * 32 + c0;
#pragma unroll
  for (int i = 0; i < 4; i++) *(float4*)(hv + 4 * i) = *(const float4*)(rp + 4 * i);
  int o0 = off[n], o1 = o0 + deg[n];
  for (int idx = o0; idx < o1; idx++) {
    const float* mp = msgbuf + slot[idx] * 32 + c0;
#pragma unroll
    for (int i = 0; i < 4; i++) {
      float4 mv = *(const float4*)(mp + 4 * i);
      hv[4 * i + 0] += mv.x; hv[4 * i + 1] += mv.y;
      hv[4 * i + 2] += mv.z; hv[4 * i + 3] += mv.w;
    }
  }
#pragma unroll
  for (int j = 0; j < 16; j++) hv[j] = fmaxf(hv[j], 0.f);
  // pair-exchange: a0 = h1[0..16), a1 = h1[16..32)  (selects, constant indices)
  float a0[16], a1[16];
#pragma unroll
  for (int j = 0; j < 16; j++) {
    float o = __shfl_xor(hv[j], 1);
    a0[j] = half ? o : hv[j];
    a1[j] = half ? hv[j] : o;
  }
  const float* W = half ? Wr : Wl;
  const float* bb = half ? br : bl;
  float ov[32];
#pragma unroll
  for (int j = 0; j < 32; j++) ov[j] = bb[j];
#pragma unroll
  for (int i = 0; i < 16; i++) {
    float u = a0[i], v = a1[i];
#pragma unroll
    for (int j = 0; j < 32; j++)
      ov[j] += u * W[i * 32 + j] + v * W[(16 + i) * 32 + j];
  }
  float* dst = (half ? xr : xl) + n * 32;
#pragma unroll
  for (int i = 0; i < 8; i++) *(float4*)(dst + 4 * i) = *(float4*)(ov + 4 * i);
}

// ---- GAT node pass (4 threads/node = 1/head): softmax + weighted gather -----
__global__ void __launch_bounds__(256) k_gat_node(
    const int* __restrict__ ei,
    const float* __restrict__ xl, const float* __restrict__ xr,
    const int* __restrict__ off, const int* __restrict__ deg,
    const int* __restrict__ slot,
    const float* __restrict__ att, const float* __restrict__ bias_gat,
    float* __restrict__ h2) {
  int t = blockIdx.x * blockDim.x + threadIdx.x;
  if (t >= 4 * NN) return;
  int n = t >> 2, hh = t & 3;
  const float* xrp = xr + n * 32 + hh * 8;
  const float* xsp = xl + n * 32 + hh * 8;
  const float* atp = att + hh * 8;
  float xrv[8], attv[8], xself[8];
  *(float4*)(xrv)      = *(const float4*)(xrp);
  *(float4*)(xrv + 4)  = *(const float4*)(xrp + 4);
  *(float4*)(attv)     = *(const float4*)(atp);
  *(float4*)(attv + 4) = *(const float4*)(atp + 4);
  *(float4*)(xself)    = *(const float4*)(xsp);
  *(float4*)(xself + 4)= *(const float4*)(xsp + 4);
  // self-loop logit seeds the max
  float slg = 0.f;
#pragma unroll
  for (int dg = 0; dg < 8; dg++) {
    float v = xself[dg] + xrv[dg];
    v = (v > 0.f) ? v : 0.2f * v;
    slg += v * attv[dg];
  }
  float mx = slg;
  int o0 = off[n], o1 = o0 + deg[n];
  for (int idx = o0; idx < o1; idx++) {
    const float* xp = xl + ei[slot[idx]] * 32 + hh * 8;
    float xv[8];
    *(float4*)(xv)     = *(const float4*)(xp);
    *(float4*)(xv + 4) = *(const float4*)(xp + 4);
    float lg = 0.f;
#pragma unroll
    for (int dg = 0; dg < 8; dg++) {
      float v = xv[dg] + xrv[dg];
      v = (v > 0.f) ? v : 0.2f * v;
      lg += v * attv[dg];
    }
    mx = fmaxf(mx, lg);
  }
  float a = __expf(slg - mx);
  float den = a;
  float accv[8];
#pragma unroll
  for (int dg = 0; dg < 8; dg++) accv[dg] = a * xself[dg];
  for (int idx = o0; idx < o1; idx++) {
    const float* xp = xl + ei[slot[idx]] * 32 + hh * 8;
    float xv[8];
    *(float4*)(xv)     = *(const float4*)(xp);
    *(float4*)(xv + 4) = *(const float4*)(xp + 4);
    float lg = 0.f;
#pragma unroll
    for (int dg = 0; dg < 8; dg++) {
      float v = xv[dg] + xrv[dg];
      v = (v > 0.f) ? v : 0.2f * v;
      lg += v * attv[dg];
    }
    float w = __expf(lg - mx);
    den += w;
#pragma unroll
    for (int dg = 0; dg < 8; dg++) accv[dg] += w * xv[dg];
  }
  float sc = 1.f / (den + 1e-16f);
  float hv[8];
#pragma unroll
  for (int dg = 0; dg < 8; dg++)
    hv[dg] = fmaxf(accv[dg] * sc + bias_gat[hh * 8 + dg], 0.f);
  float* op = h2 + n * 32 + hh * 8;
  *(float4*)(op)     = *(float4*)(hv);
  *(float4*)(op + 4) = *(float4*)(hv + 4);
}

// ---- node pass 2 (2 threads/node): root2 half-GEMM + half-gather + classifier
__global__ void __launch_bounds__(256) k_node2(
    const float* __restrict__ h2, const float* __restrict__ msgbuf,
    const int* __restrict__ off, const int* __restrict__ deg,
    const int* __restrict__ slot,
    const float* __restrict__ root2, const float* __restrict__ bias2,
    const float* __restrict__ Wlin, const float* __restrict__ blin,
    float* __restrict__ out) {
  int t = blockIdx.x * blockDim.x + threadIdx.x;
  if (t >= 2 * NN) return;
  int n = t >> 1, half = t & 1;
  int c0 = half * 16;
  float h2v[32];
#pragma unroll
  for (int i = 0; i < 8; i++) *(float4*)(h2v + 4 * i) = *(const float4*)(h2 + n * 32 + 4 * i);
  float rv[16];
#pragma unroll
  for (int j = 0; j < 16; j++) rv[j] = bias2[c0 + j];
#pragma unroll
  for (int i = 0; i < 32; i++) {
    float hi = h2v[i];
#pragma unroll
    for (int j = 0; j < 16; j++) rv[j] += hi * root2[i * 32 + c0 + j];
  }
  int o0 = off[n], o1 = o0 + deg[n];
  for (int idx = o0; idx < o1; idx++) {
    const float* mp = msgbuf + slot[idx] * 32 + c0;
#pragma unroll
    for (int i = 0; i < 4; i++) {
      float4 mv = *(const float4*)(mp + 4 * i);
      rv[4 * i + 0] += mv.x; rv[4 * i + 1] += mv.y;
      rv[4 * i + 2] += mv.z; rv[4 * i + 3] += mv.w;
    }
  }
#pragma unroll
  for (int j = 0; j < 16; j++) rv[j] = fmaxf(rv[j], 0.f);
  float ov[10];
#pragma unroll
  for (int c = 0; c < 10; c++) ov[c] = 0.f;
#pragma unroll
  for (int j = 0; j < 16; j++) {
    float hj = rv[j];
#pragma unroll
    for (int c = 0; c < 10; c++) ov[c] += hj * Wlin[(c0 + j) * 10 + c];
  }
#pragma unroll
  for (int c = 0; c < 10; c++) ov[c] += __shfl_xor(ov[c], 1);
  if (half == 0) {
#pragma unroll
    for (int c = 0; c < 5; c++) out[n * 10 + c] = ov[c] + blin[c];
  } else {
#pragma unroll
    for (int c = 5; c < 10; c++) out[n * 10 + c] = ov[c] + blin[c];
  }
}

extern "C" void kernel_launch(void* const* d_in, const int* in_sizes, int n_in,
                              void* d_out, int out_size, void* d_ws, size_t ws_size,
                              hipStream_t stream) {
  const float* x         = (const float*)d_in[0];
  const float* edge_attr = (const float*)d_in[1];
  const int*   ei        = (const int*)d_in[2];   // [2,E]: src = ei, dst = ei+NE
  const float* We_node   = (const float*)d_in[3];
  const float* be_node   = (const float*)d_in[4];
  const float* We_edge   = (const float*)d_in[5];
  const float* be_edge   = (const float*)d_in[6];
  const float* W1_nn     = (const float*)d_in[7];
  const float* b1_nn     = (const float*)d_in[8];
  const float* root1     = (const float*)d_in[9];
  const float* bias1     = (const float*)d_in[10];
  const float* Wl        = (const float*)d_in[11];
  const float* bl        = (const float*)d_in[12];
  const float* Wr        = (const float*)d_in[13];
  const float* br        = (const float*)d_in[14];
  const float* att       = (const float*)d_in[15];
  const float* bias_gat  = (const float*)d_in[16];
  const float* W2_nn     = (const float*)d_in[17];
  const float* b2_nn     = (const float*)d_in[18];
  const float* root2     = (const float*)d_in[19];
  const float* bias2     = (const float*)d_in[20];
  const float* Wlin      = (const float*)d_in[21];
  const float* blin      = (const float*)d_in[22];
  float* out = (float*)d_out;

  float* ws = (float*)d_ws;
  float* h0h2  = ws;                 // NN*32 (h0, later h2)
  float* ea    = h0h2 + NN * 32;     // NE*32
  float* r1pre = ea + NE * 32;       // NN*32
  float* xl    = r1pre + NN * 32;    // NN*32
  float* xr    = xl + NN * 32;       // NN*32
  float* msgbuf = xr + NN * 32;      // NE*32 (reused conv1/conv2)
  float* fend  = msgbuf + NE * 32;
  __hip_bfloat16* Bswz1 = (__hip_bfloat16*)fend;            // 33792 bf16
  __hip_bfloat16* Bswz2 = (__hip_bfloat16*)(fend + 17000);  // 33792 bf16
  int* deg    = (int*)(fend + 34000);   // NN
  int* off    = deg + NN;               // NN
  int* cursor = off + NN;               // NN
  int* bsum   = cursor + NN;            // 128
  int* slot   = bsum + 128;             // NE

  const int B = 256;
  k_zero<<<NBN, B, 0, stream>>>(deg);
  k_prep<<<NBN + NBE + NBP + NBC, B, 0, stream>>>(
      x, edge_attr, ei, We_node, be_node, We_edge, be_edge, root1, bias1,
      W1_nn, b1_nn, W2_nn, b2_nn, h0h2, r1pre, ea, Bswz1, Bswz2, deg);
  k_scan1<<<NBN, B, 0, stream>>>(deg, bsum);
  k_scan3<<<NBN, B, 0, stream>>>(deg, bsum, off, cursor);
  k_csr_fill<<<(NE + B - 1) / B, B, 0, stream>>>(ei, cursor, slot);
  k_nnconv_mfma<<<512, B, 65536, stream>>>(h0h2, ea, Bswz1, ei, msgbuf);
  k_node1<<<(2 * NN + B - 1) / B, B, 0, stream>>>(r1pre, msgbuf, off, deg, slot, Wl, bl, Wr, br, xl, xr);
  k_gat_node<<<(4 * NN + B - 1) / B, B, 0, stream>>>(ei, xl, xr, off, deg, slot, att, bias_gat, h0h2);
  k_nnconv_mfma<<<512, B, 65536, stream>>>(h0h2, ea, Bswz2, ei, msgbuf);
  k_node2<<<(2 * NN + B - 1) / B, B, 0, stream>>>(h0h2, msgbuf, off, deg, slot, root2, bias2, Wlin, blin, out);
}

// Round 6
// 130.250 us; speedup vs baseline: 21.6789x; 1.1418x over previous
//
#include <hip/hip_runtime.h>
#include <hip/hip_bf16.h>
#include <math.h>

#define NN 25000
#define NE 100000
#define NTILES (NE / 16)   // 6250 edge tiles of 16
#define NBN 98             // ceil(NN/256)
#define NBE 391            // ceil(NE/256)
#define NBP 264            // ceil(2*33792/256)
#define NBC 391            // ceil(NE/256)

typedef __attribute__((ext_vector_type(8))) short short8;
typedef __attribute__((ext_vector_type(4))) float f32x4;

// pack 8 fp32 -> short8 of bf16 via HW packed convert (RTNE)
static __device__ __forceinline__ short8 pack_bf8(const float* p) {
  union { short8 s; unsigned int u[4]; } r;
#pragma unroll
  for (int q = 0; q < 4; q++)
    asm("v_cvt_pk_bf16_f32 %0, %1, %2" : "=v"(r.u[q]) : "v"(p[2 * q]), "v"(p[2 * q + 1]));
  return r.s;
}

// ==== zero deg ====
__global__ void __launch_bounds__(256) k_zero(int* __restrict__ deg) {
  int n = blockIdx.x * 256 + threadIdx.x;
  if (n < NN) deg[n] = 0;
}

// ==== fused prep: node encoder | edge encoder | W-pack x2 | degree count ====
__global__ void __launch_bounds__(256) k_prep(
    const float* __restrict__ x, const float* __restrict__ eattr,
    const int* __restrict__ ei,
    const float* __restrict__ We_node, const float* __restrict__ be_node,
    const float* __restrict__ We_edge, const float* __restrict__ be_edge,
    const float* __restrict__ root1, const float* __restrict__ bias1,
    const float* __restrict__ W1, const float* __restrict__ b1,
    const float* __restrict__ W2, const float* __restrict__ b2,
    float* __restrict__ h0, float* __restrict__ r1pre, float* __restrict__ ea,
    __hip_bfloat16* __restrict__ Bswz1, __hip_bfloat16* __restrict__ Bswz2,
    int* __restrict__ deg) {
  int b = blockIdx.x;
  int tid = threadIdx.x;
  if (b < NBN) {
    int n = b * 256 + tid;
    if (n >= NN) return;
    float xv[32], hv[32], rv[32];
#pragma unroll
    for (int i = 0; i < 8; i++) *(float4*)(xv + 4 * i) = *(const float4*)(x + n * 32 + 4 * i);
#pragma unroll
    for (int j = 0; j < 32; j++) hv[j] = be_node[j];
#pragma unroll
    for (int i = 0; i < 32; i++) {
      float xi = xv[i];
#pragma unroll
      for (int j = 0; j < 32; j++) hv[j] += xi * We_node[i * 32 + j];
    }
#pragma unroll
    for (int i = 0; i < 8; i++) *(float4*)(h0 + n * 32 + 4 * i) = *(float4*)(hv + 4 * i);
#pragma unroll
    for (int j = 0; j < 32; j++) rv[j] = bias1[j];
#pragma unroll
    for (int i = 0; i < 32; i++) {
      float hi = hv[i];
#pragma unroll
      for (int j = 0; j < 32; j++) rv[j] += hi * root1[i * 32 + j];
    }
#pragma unroll
    for (int i = 0; i < 8; i++) *(float4*)(r1pre + n * 32 + 4 * i) = *(float4*)(rv + 4 * i);
  } else if (b < NBN + NBE) {
    int e = (b - NBN) * 256 + tid;
    if (e >= NE) return;
    float av[16], ov[32];
#pragma unroll
    for (int i = 0; i < 4; i++) *(float4*)(av + 4 * i) = *(const float4*)(eattr + e * 16 + 4 * i);
#pragma unroll
    for (int j = 0; j < 32; j++) ov[j] = be_edge[j];
#pragma unroll
    for (int k = 0; k < 16; k++) {
      float ak = av[k];
#pragma unroll
      for (int j = 0; j < 32; j++) ov[j] += ak * We_edge[k * 32 + j];
    }
#pragma unroll
    for (int i = 0; i < 8; i++) *(float4*)(ea + e * 32 + 4 * i) = *(float4*)(ov + 4 * i);
  } else if (b < NBN + NBE + NBP) {
    int idx = (b - NBN - NBE) * 256 + tid;
    if (idx >= 2 * 33792) return;
    int sel = idx >= 33792;
    int r = idx - sel * 33792;
    int j = r & 7;
    int l = (r >> 3) & 63;
    int nt = (r >> 9) & 1;
    int t = r >> 10;
    int i = 8 * (l >> 4) + j;
    int o = nt * 16 + (l & 15);
    const float* W = sel ? W2 : W1;
    const float* bb = sel ? b2 : b1;
    float v = (t < 32) ? W[t * 1024 + i * 32 + o] : bb[i * 32 + o];
    (sel ? Bswz2 : Bswz1)[r] = __float2bfloat16(v);
  } else {
    int e = (b - NBN - NBE - NBP) * 256 + tid;
    if (e < NE) atomicAdd(&deg[ei[NE + e]], 1);
  }
}

// ==== scan stage 1: per-block sums of deg ====
__global__ void __launch_bounds__(256) k_scan1(const int* __restrict__ deg,
                                               int* __restrict__ bsum) {
  __shared__ int s[256];
  int tid = threadIdx.x;
  int n = blockIdx.x * 256 + tid;
  s[tid] = (n < NN) ? deg[n] : 0;
  __syncthreads();
  for (int d = 128; d > 0; d >>= 1) {
    if (tid < d) s[tid] += s[tid + d];
    __syncthreads();
  }
  if (tid == 0) bsum[blockIdx.x] = s[0];
}

// ==== scan stage 2: block-local exclusive scan + bsum prefix -> off/cursor ===
__global__ void __launch_bounds__(256) k_scan3(const int* __restrict__ deg,
                                               const int* __restrict__ bsum,
                                               int* __restrict__ off,
                                               int* __restrict__ cursor) {
  __shared__ int sb[128];
  __shared__ int s[256];
  int tid = threadIdx.x;
  if (tid < 128) sb[tid] = (tid < NBN) ? bsum[tid] : 0;
  int n = blockIdx.x * 256 + tid;
  int v = (n < NN) ? deg[n] : 0;
  s[tid] = v;
  __syncthreads();
  for (int d = 1; d < 128; d <<= 1) {
    int t = 0;
    if (tid < 128 && tid >= d) t = sb[tid - d];
    __syncthreads();
    if (tid < 128) sb[tid] += t;
    __syncthreads();
  }
  for (int d = 1; d < 256; d <<= 1) {
    int t = (tid >= d) ? s[tid - d] : 0;
    __syncthreads();
    s[tid] += t;
    __syncthreads();
  }
  int base = (blockIdx.x > 0) ? sb[blockIdx.x - 1] : 0;
  int excl = s[tid] - v + base;
  if (n < NN) { off[n] = excl; cursor[n] = excl; }
}

// ==== CSR fill: slot (csr->edge) and perm (edge->csr) ====
__global__ void k_csr_fill(const int* __restrict__ ei, int* __restrict__ cursor,
                           int* __restrict__ slot, int* __restrict__ perm) {
  int e = blockIdx.x * blockDim.x + threadIdx.x;
  if (e >= NE) return;
  int d = ei[NE + e];
  int p = atomicAdd(&cursor[d], 1);
  slot[p] = e;
  perm[e] = p;
}

// ---- NNConv as MFMA GEMM; epilogue stores msgbuf in CSR order (perm) --------
__global__ void __launch_bounds__(256) k_nnconv_mfma(
    const float* __restrict__ hin, const float* __restrict__ ea,
    const __hip_bfloat16* __restrict__ Bswz, const int* __restrict__ ei,
    const int* __restrict__ perm, float* __restrict__ msgbuf) {
  extern __shared__ short8 bsh[];   // 32 steps * 2 ntiles * 64 lanes = 64 KB
  int tid = threadIdx.x;
  {
    uint4* s4 = (uint4*)bsh;
    const uint4* g4 = (const uint4*)Bswz;
#pragma unroll
    for (int it = 0; it < 16; it++) s4[tid + 256 * it] = g4[tid + 256 * it];
  }
  __syncthreads();

  int wid = tid >> 6;
  int lane = tid & 63;
  int lrow = lane & 15;        // A row / C col
  int lk8 = (lane >> 4) * 8;   // k-offset of this lane's 8 A elems

  for (int tile = blockIdx.x * 4 + wid; tile < NTILES; tile += gridDim.x * 4) {
    int e0 = tile * 16;
    int e = e0 + lrow;
    int src = ei[e];
    float hf[8];
    *(float4*)(hf)     = *(const float4*)(hin + src * 32 + lk8);
    *(float4*)(hf + 4) = *(const float4*)(hin + src * 32 + lk8 + 4);
    float eav[32];
#pragma unroll
    for (int c = 0; c < 8; c++)
      *(float4*)(eav + 4 * c) = *(const float4*)(ea + e * 32 + 4 * c);
    short8 af_bias = pack_bf8(hf);   // bias-step A frag, reused

    f32x4 a00 = {0.f, 0.f, 0.f, 0.f}, a01 = a00, a10 = a00, a11 = a00;
#pragma unroll
    for (int t = 0; t < 32; t++) {
      float et = eav[t];
      float pr[8];
#pragma unroll
      for (int j = 0; j < 8; j++) pr[j] = et * hf[j];
      short8 af = pack_bf8(pr);
      short8 b0 = bsh[(t * 2 + 0) * 64 + lane];
      short8 b1 = bsh[(t * 2 + 1) * 64 + lane];
      if (t & 1) {
        a01 = __builtin_amdgcn_mfma_f32_16x16x32_bf16(af, b0, a01, 0, 0, 0);
        a11 = __builtin_amdgcn_mfma_f32_16x16x32_bf16(af, b1, a11, 0, 0, 0);
      } else {
        a00 = __builtin_amdgcn_mfma_f32_16x16x32_bf16(af, b0, a00, 0, 0, 0);
        a10 = __builtin_amdgcn_mfma_f32_16x16x32_bf16(af, b1, a10, 0, 0, 0);
      }
    }
    // bias K-step: A = h itself, B from global (L2-cached)
    {
      const short8* gb = (const short8*)Bswz;
      short8 b0 = gb[(32 * 2 + 0) * 64 + lane];
      short8 b1 = gb[(32 * 2 + 1) * 64 + lane];
      a00 = __builtin_amdgcn_mfma_f32_16x16x32_bf16(af_bias, b0, a00, 0, 0, 0);
      a10 = __builtin_amdgcn_mfma_f32_16x16x32_bf16(af_bias, b1, a10, 0, 0, 0);
    }
    f32x4 c0 = a00 + a01;
    f32x4 c1 = a10 + a11;
    int r0 = (lane >> 4) * 4;
#pragma unroll
    for (int r = 0; r < 4; r++) {
      int p = perm[e0 + r0 + r];
      float* mp = msgbuf + p * 32 + lrow;
      mp[0]  = c0[r];
      mp[16] = c1[r];
    }
  }
}

// ---- node pass 1 (2 threads/node): stream CSR msgbuf, pair-exchange, GEMM ---
__global__ void __launch_bounds__(256) k_node1(
    const float* __restrict__ r1pre, const float* __restrict__ msgbuf,
    const int* __restrict__ off, const int* __restrict__ deg,
    const float* __restrict__ Wl, const float* __restrict__ bl,
    const float* __restrict__ Wr, const float* __restrict__ br,
    float* __restrict__ xl, float* __restrict__ xr) {
  int t = blockIdx.x * blockDim.x + threadIdx.x;
  if (t >= 2 * NN) return;
  int n = t >> 1, half = t & 1;
  int c0 = half * 16;
  float hv[16];
  const float* rp = r1pre + n * 32 + c0;
#pragma unroll
  for (int i = 0; i < 4; i++) *(float4*)(hv + 4 * i) = *(const float4*)(rp + 4 * i);
  int o0 = off[n], o1 = o0 + deg[n];
  for (int idx = o0; idx < o1; idx++) {
    const float* mp = msgbuf + idx * 32 + c0;
#pragma unroll
    for (int i = 0; i < 4; i++) {
      float4 mv = *(const float4*)(mp + 4 * i);
      hv[4 * i + 0] += mv.x; hv[4 * i + 1] += mv.y;
      hv[4 * i + 2] += mv.z; hv[4 * i + 3] += mv.w;
    }
  }
#pragma unroll
  for (int j = 0; j < 16; j++) hv[j] = fmaxf(hv[j], 0.f);
  float a0[16], a1[16];
#pragma unroll
  for (int j = 0; j < 16; j++) {
    float o = __shfl_xor(hv[j], 1);
    a0[j] = half ? o : hv[j];
    a1[j] = half ? hv[j] : o;
  }
  const float* W = half ? Wr : Wl;
  const float* bb = half ? br : bl;
  float ov[32];
#pragma unroll
  for (int j = 0; j < 32; j++) ov[j] = bb[j];
#pragma unroll
  for (int i = 0; i < 16; i++) {
    float u = a0[i], v = a1[i];
#pragma unroll
    for (int j = 0; j < 32; j++)
      ov[j] += u * W[i * 32 + j] + v * W[(16 + i) * 32 + j];
  }
  float* dst = (half ? xr : xl) + n * 32;
#pragma unroll
  for (int i = 0; i < 8; i++) *(float4*)(dst + 4 * i) = *(float4*)(ov + 4 * i);
}

// ---- gather xl into CSR order (4 threads/edge, coalesced) -------------------
__global__ void __launch_bounds__(256) k_gather_xls(
    const int* __restrict__ ei, const int* __restrict__ slot,
    const float* __restrict__ xl, float* __restrict__ xls) {
  int t = blockIdx.x * 256 + threadIdx.x;
  if (t >= 4 * NE) return;
  int idx = t >> 2, q = t & 3;
  int s = ei[slot[idx]];
  const float* sp = xl + s * 32 + q * 8;
  float* dp = xls + idx * 32 + q * 8;
  float4 v0 = *(const float4*)(sp);
  float4 v1 = *(const float4*)(sp + 4);
  *(float4*)(dp) = v0;
  *(float4*)(dp + 4) = v1;
}

// ---- GAT node pass (4 threads/node = 1/head): streams xls -------------------
__global__ void __launch_bounds__(256) k_gat_node(
    const float* __restrict__ xl, const float* __restrict__ xr,
    const float* __restrict__ xls,
    const int* __restrict__ off, const int* __restrict__ deg,
    const float* __restrict__ att, const float* __restrict__ bias_gat,
    float* __restrict__ h2) {
  int t = blockIdx.x * blockDim.x + threadIdx.x;
  if (t >= 4 * NN) return;
  int n = t >> 2, hh = t & 3;
  const float* xrp = xr + n * 32 + hh * 8;
  const float* xsp = xl + n * 32 + hh * 8;
  const float* atp = att + hh * 8;
  float xrv[8], attv[8], xself[8];
  *(float4*)(xrv)      = *(const float4*)(xrp);
  *(float4*)(xrv + 4)  = *(const float4*)(xrp + 4);
  *(float4*)(attv)     = *(const float4*)(atp);
  *(float4*)(attv + 4) = *(const float4*)(atp + 4);
  *(float4*)(xself)    = *(const float4*)(xsp);
  *(float4*)(xself + 4)= *(const float4*)(xsp + 4);
  float slg = 0.f;
#pragma unroll
  for (int dg = 0; dg < 8; dg++) {
    float v = xself[dg] + xrv[dg];
    v = (v > 0.f) ? v : 0.2f * v;
    slg += v * attv[dg];
  }
  float mx = slg;
  int o0 = off[n], o1 = o0 + deg[n];
  for (int idx = o0; idx < o1; idx++) {
    const float* xp = xls + idx * 32 + hh * 8;
    float xv[8];
    *(float4*)(xv)     = *(const float4*)(xp);
    *(float4*)(xv + 4) = *(const float4*)(xp + 4);
    float lg = 0.f;
#pragma unroll
    for (int dg = 0; dg < 8; dg++) {
      float v = xv[dg] + xrv[dg];
      v = (v > 0.f) ? v : 0.2f * v;
      lg += v * attv[dg];
    }
    mx = fmaxf(mx, lg);
  }
  float a = __expf(slg - mx);
  float den = a;
  float accv[8];
#pragma unroll
  for (int dg = 0; dg < 8; dg++) accv[dg] = a * xself[dg];
  for (int idx = o0; idx < o1; idx++) {
    const float* xp = xls + idx * 32 + hh * 8;
    float xv[8];
    *(float4*)(xv)     = *(const float4*)(xp);
    *(float4*)(xv + 4) = *(const float4*)(xp + 4);
    float lg = 0.f;
#pragma unroll
    for (int dg = 0; dg < 8; dg++) {
      float v = xv[dg] + xrv[dg];
      v = (v > 0.f) ? v : 0.2f * v;
      lg += v * attv[dg];
    }
    float w = __expf(lg - mx);
    den += w;
#pragma unroll
    for (int dg = 0; dg < 8; dg++) accv[dg] += w * xv[dg];
  }
  float sc = 1.f / (den + 1e-16f);
  float hv[8];
#pragma unroll
  for (int dg = 0; dg < 8; dg++)
    hv[dg] = fmaxf(accv[dg] * sc + bias_gat[hh * 8 + dg], 0.f);
  float* op = h2 + n * 32 + hh * 8;
  *(float4*)(op)     = *(float4*)(hv);
  *(float4*)(op + 4) = *(float4*)(hv + 4);
}

// ---- node pass 2 (2 threads/node): root2 half-GEMM + stream + classifier ----
__global__ void __launch_bounds__(256) k_node2(
    const float* __restrict__ h2, const float* __restrict__ msgbuf,
    const int* __restrict__ off, const int* __restrict__ deg,
    const float* __restrict__ root2, const float* __restrict__ bias2,
    const float* __restrict__ Wlin, const float* __restrict__ blin,
    float* __restrict__ out) {
  int t = blockIdx.x * blockDim.x + threadIdx.x;
  if (t >= 2 * NN) return;
  int n = t >> 1, half = t & 1;
  int c0 = half * 16;
  float h2v[32];
#pragma unroll
  for (int i = 0; i < 8; i++) *(float4*)(h2v + 4 * i) = *(const float4*)(h2 + n * 32 + 4 * i);
  float rv[16];
#pragma unroll
  for (int j = 0; j < 16; j++) rv[j] = bias2[c0 + j];
#pragma unroll
  for (int i = 0; i < 32; i++) {
    float hi = h2v[i];
#pragma unroll
    for (int j = 0; j < 16; j++) rv[j] += hi * root2[i * 32 + c0 + j];
  }
  int o0 = off[n], o1 = o0 + deg[n];
  for (int idx = o0; idx < o1; idx++) {
    const float* mp = msgbuf + idx * 32 + c0;
#pragma unroll
    for (int i = 0; i < 4; i++) {
      float4 mv = *(const float4*)(mp + 4 * i);
      rv[4 * i + 0] += mv.x; rv[4 * i + 1] += mv.y;
      rv[4 * i + 2] += mv.z; rv[4 * i + 3] += mv.w;
    }
  }
#pragma unroll
  for (int j = 0; j < 16; j++) rv[j] = fmaxf(rv[j], 0.f);
  float ov[10];
#pragma unroll
  for (int c = 0; c < 10; c++) ov[c] = 0.f;
#pragma unroll
  for (int j = 0; j < 16; j++) {
    float hj = rv[j];
#pragma unroll
    for (int c = 0; c < 10; c++) ov[c] += hj * Wlin[(c0 + j) * 10 + c];
  }
#pragma unroll
  for (int c = 0; c < 10; c++) ov[c] += __shfl_xor(ov[c], 1);
  if (half == 0) {
#pragma unroll
    for (int c = 0; c < 5; c++) out[n * 10 + c] = ov[c] + blin[c];
  } else {
#pragma unroll
    for (int c = 5; c < 10; c++) out[n * 10 + c] = ov[c] + blin[c];
  }
}

extern "C" void kernel_launch(void* const* d_in, const int* in_sizes, int n_in,
                              void* d_out, int out_size, void* d_ws, size_t ws_size,
                              hipStream_t stream) {
  const float* x         = (const float*)d_in[0];
  const float* edge_attr = (const float*)d_in[1];
  const int*   ei        = (const int*)d_in[2];   // [2,E]: src = ei, dst = ei+NE
  const float* We_node   = (const float*)d_in[3];
  const float* be_node   = (const float*)d_in[4];
  const float* We_edge   = (const float*)d_in[5];
  const float* be_edge   = (const float*)d_in[6];
  const float* W1_nn     = (const float*)d_in[7];
  const float* b1_nn     = (const float*)d_in[8];
  const float* root1     = (const float*)d_in[9];
  const float* bias1     = (const float*)d_in[10];
  const float* Wl        = (const float*)d_in[11];
  const float* bl        = (const float*)d_in[12];
  const float* Wr        = (const float*)d_in[13];
  const float* br        = (const float*)d_in[14];
  const float* att       = (const float*)d_in[15];
  const float* bias_gat  = (const float*)d_in[16];
  const float* W2_nn     = (const float*)d_in[17];
  const float* b2_nn     = (const float*)d_in[18];
  const float* root2     = (const float*)d_in[19];
  const float* bias2     = (const float*)d_in[20];
  const float* Wlin      = (const float*)d_in[21];
  const float* blin      = (const float*)d_in[22];
  float* out = (float*)d_out;

  float* ws = (float*)d_ws;
  float* h0h2  = ws;                 // NN*32 (h0, later h2)
  float* ea    = h0h2 + NN * 32;     // NE*32
  float* r1pre = ea + NE * 32;       // NN*32
  float* xl    = r1pre + NN * 32;    // NN*32
  float* xr    = xl + NN * 32;       // NN*32
  float* msgbuf = xr + NN * 32;      // NE*32 (CSR order; reused conv1/conv2)
  float* xls   = msgbuf + NE * 32;   // NE*32 (xl gathered to CSR order)
  float* fend  = xls + NE * 32;
  __hip_bfloat16* Bswz1 = (__hip_bfloat16*)fend;            // 33792 bf16
  __hip_bfloat16* Bswz2 = (__hip_bfloat16*)(fend + 17000);  // 33792 bf16
  int* deg    = (int*)(fend + 34000);   // NN
  int* off    = deg + NN;               // NN
  int* cursor = off + NN;               // NN
  int* bsum   = cursor + NN;            // 128
  int* slot   = bsum + 128;             // NE
  int* perm   = slot + NE;              // NE

  const int B = 256;
  k_zero<<<NBN, B, 0, stream>>>(deg);
  k_prep<<<NBN + NBE + NBP + NBC, B, 0, stream>>>(
      x, edge_attr, ei, We_node, be_node, We_edge, be_edge, root1, bias1,
      W1_nn, b1_nn, W2_nn, b2_nn, h0h2, r1pre, ea, Bswz1, Bswz2, deg);
  k_scan1<<<NBN, B, 0, stream>>>(deg, bsum);
  k_scan3<<<NBN, B, 0, stream>>>(deg, bsum, off, cursor);
  k_csr_fill<<<(NE + B - 1) / B, B, 0, stream>>>(ei, cursor, slot, perm);
  k_nnconv_mfma<<<512, B, 65536, stream>>>(h0h2, ea, Bswz1, ei, perm, msgbuf);
  k_node1<<<(2 * NN + B - 1) / B, B, 0, stream>>>(r1pre, msgbuf, off, deg, Wl, bl, Wr, br, xl, xr);
  k_gather_xls<<<(4 * NE + B - 1) / B, B, 0, stream>>>(ei, slot, xl, xls);
  k_gat_node<<<(4 * NN + B - 1) / B, B, 0, stream>>>(xl, xr, xls, off, deg, att, bias_gat, h0h2);
  k_nnconv_mfma<<<512, B, 65536, stream>>>(h0h2, ea, Bswz2, ei, perm, msgbuf);
  k_node2<<<(2 * NN + B - 1) / B, B, 0, stream>>>(h0h2, msgbuf, off, deg, root2, bias2, Wlin, blin, out);
}